// Round 9
// baseline (1144.938 us; speedup 1.0000x reference)
//
#include <hip/hip_runtime.h>
#include <math.h>

#define LSEQ 384
#define HD 256
#define PDIM 64
#define NHEAD 4
#define NBINS 65
#define BATCH 2
#define NTT (LSEQ / 16)
#define NTRI (NTT * (NTT + 1) / 2)

typedef __attribute__((ext_vector_type(8))) short bf16x8;
typedef __attribute__((ext_vector_type(16))) float f32x16;
typedef __attribute__((ext_vector_type(4))) float f32x4;
typedef __attribute__((ext_vector_type(4))) unsigned u32x4;
typedef __attribute__((ext_vector_type(4))) short s16x4;
#define MFMA32(a, b, c) __builtin_amdgcn_mfma_f32_32x32x16_bf16(a, b, c, 0, 0, 0)

// ---- DPP-based wave64 reductions (VALU pipe, not LDS) ----
template<int CTRL, int RMASK>
__device__ __forceinline__ float dpp_sum_step(float v) {
    int x = __builtin_amdgcn_update_dpp(0, __float_as_int(v), CTRL, RMASK, 0xf, true);
    return v + __int_as_float(x);
}
template<int CTRL, int RMASK>
__device__ __forceinline__ float dpp_max_step(float v) {
    int x = __builtin_amdgcn_update_dpp(__float_as_int(v), __float_as_int(v), CTRL, RMASK, 0xf, false);
    return fmaxf(v, __int_as_float(x));
}
__device__ __forceinline__ float wsum(float v) {
    v = dpp_sum_step<0x111, 0xf>(v);
    v = dpp_sum_step<0x112, 0xf>(v);
    v = dpp_sum_step<0x114, 0xf>(v);
    v = dpp_sum_step<0x118, 0xf>(v);
    v = dpp_sum_step<0x142, 0xa>(v);
    v = dpp_sum_step<0x143, 0xc>(v);
    return __int_as_float(__builtin_amdgcn_readlane(__float_as_int(v), 63));
}
__device__ __forceinline__ float wmax(float v) {
    v = dpp_max_step<0x111, 0xf>(v);
    v = dpp_max_step<0x112, 0xf>(v);
    v = dpp_max_step<0x114, 0xf>(v);
    v = dpp_max_step<0x118, 0xf>(v);
    v = dpp_max_step<0x142, 0xa>(v);
    v = dpp_max_step<0x143, 0xc>(v);
    return __int_as_float(__builtin_amdgcn_readlane(__float_as_int(v), 63));
}

// gelu with erf via Abramowitz-Stegun 7.1.26 (|erf err| <= 1.5e-7), built on
// HIP fast intrinsics (__fdividef -> v_rcp, __expf -> v_exp) so the compiler
// can schedule them (round-5's inline-asm version defeated the scheduler).
// ~14 VALU ops vs ~27 for libm erff; erff was ~50% of pair_upd's VALU-busy.
__device__ __forceinline__ float gelu_erf(float x) {
    float az = fabsf(x) * 0.70710678f;
    float t = __fdividef(1.0f, fmaf(0.3275911f, az, 1.0f));
    float p = fmaf(fmaf(fmaf(fmaf(1.061405429f, t, -1.453152027f), t,
                  1.421413741f), t, -0.284496736f), t, 0.254829592f) * t;
    float e = __expf(-az * az);
    float er = fmaf(-p, e, 1.0f);
    float s = x < 0.0f ? -er : er;
    return 0.5f * x * (1.0f + s);
}

// bf16 RNE conversion + error-compensated split: x ~= hi + lo
__device__ __forceinline__ unsigned short f2bf(float x) {
    unsigned u = __float_as_uint(x);
    unsigned r = (u + 0x7fff + ((u >> 16) & 1)) >> 16;
    return (unsigned short)r;
}
__device__ __forceinline__ float bf2f(unsigned short h) {
    return __uint_as_float(((unsigned)h) << 16);
}
__device__ __forceinline__ void split_bf(float x, unsigned short& h, unsigned short& l) {
    h = f2bf(x);
    l = f2bf(x - bf2f(h));
}

// HW packed f32->bf16 RNE (identical rounding to f2bf), 2 values per inst.
__device__ __forceinline__ unsigned cvt_pk_bf(float lo, float hi) {
    unsigned r;
    asm("v_cvt_pk_bf16_f32 %0, %1, %2" : "=v"(r) : "v"(lo), "v"(hi));
    return r;
}
// pack 8 floats -> hi bf16x8 + lo bf16x8 (error-compensated split), as u32x4
__device__ __forceinline__ void pack8(const float* v, u32x4& h, u32x4& l) {
#pragma unroll
    for (int j = 0; j < 4; ++j) {
        float a = v[2 * j], b = v[2 * j + 1];
        unsigned hp = cvt_pk_bf(a, b);
        float ra = a - __uint_as_float(hp << 16);
        float rb = b - __uint_as_float(hp & 0xffff0000u);
        h[j] = hp;
        l[j] = cvt_pk_bf(ra, rb);
    }
}
__device__ __forceinline__ bf16x8 as_bf(u32x4 x) {
    union { u32x4 u; bf16x8 b; } c; c.u = x; return c.b;
}
// load a bf16x8 fragment from LDS (8-byte aligned, padded-stride rows)
__device__ __forceinline__ bf16x8 ld8(const short* p) {
    s16x4 a = *(const s16x4*)p;
    s16x4 b = *(const s16x4*)(p + 4);
    bf16x8 r;
    r[0] = a[0]; r[1] = a[1]; r[2] = a[2]; r[3] = a[3];
    r[4] = b[0]; r[5] = b[1]; r[6] = b[2]; r[7] = b[3];
    return r;
}

// cooperative stage of one MLP's hi/lo weight pair into padded LDS
__device__ __forceinline__ void stage_w(short (*lw)[64][68], int t,
                                        const unsigned short* __restrict__ srcA,
                                        const unsigned short* __restrict__ srcB) {
    for (int idx = t; idx < 2048; idx += 256) {
        int rr2 = idx >> 5, cc2 = (idx & 31) * 2;
        *(unsigned*)&lw[0][rr2][cc2] = *(const unsigned*)(srcA + rr2 * 64 + cc2);
        *(unsigned*)&lw[1][rr2][cc2] = *(const unsigned*)(srcB + rr2 * 64 + cc2);
    }
}

// h[b,l,:] = x[b,l,:] @ rp_w + rp_b + pos[l,:]
__global__ void k_h_init(const float* __restrict__ x, const float* __restrict__ rp_w,
                         const float* __restrict__ rp_b, const float* __restrict__ pos,
                         float* __restrict__ h) {
    __shared__ float xs[48];
    int row = blockIdx.x;            // b*L + l
    int l = row % LSEQ;
    int t = threadIdx.x;
    if (t < 48) xs[t] = x[row * 48 + t];
    __syncthreads();
    float acc = rp_b[t] + pos[l * HD + t];
#pragma unroll 8
    for (int a = 0; a < 48; ++a) acc += xs[a] * rp_w[a * HD + t];
    h[row * HD + t] = acc;
}

// pA[row,:] = h[row,:] @ wA (+ bA);  pB[row,:] = h[row,:] @ wB (+ bB)
// center!=0: subtract per-row mean (LN-mean elimination downstream)
__global__ void k_proj2(const float* __restrict__ h, const float* __restrict__ wA,
                        const float* __restrict__ wB, const float* __restrict__ bA,
                        const float* __restrict__ bB, int center,
                        float* __restrict__ pA, float* __restrict__ pB) {
    __shared__ float hs[HD];
    int row = blockIdx.x;
    int t = threadIdx.x;
    hs[t] = h[row * HD + t];
    hs[t + 128] = h[row * HD + t + 128];
    __syncthreads();
    int col = t & 63;
    const float* w = (t < 64) ? wA : wB;
    const float* bias = (t < 64) ? bA : bB;
    float acc = bias ? bias[col] : 0.0f;
#pragma unroll 8
    for (int a = 0; a < HD; ++a) acc += hs[a] * w[a * PDIM + col];
    if (center) {
        float mean = wsum(acc) * (1.0f / PDIM);
        acc -= mean;
    }
    float* p = (t < 64) ? pA : pB;
    p[row * PDIM + col] = acc;
}

// layer-0 mask ONLY: computes pair-init values in-flight (pi+pj+rel), never
// stores pair (saves 75MB write; layer-0 pair_upd recomputes init as residual).
__global__ void __launch_bounds__(64) k_mask0(
    const float* __restrict__ pi, const float* __restrict__ pj,
    const float* __restrict__ rel_emb, const float* __restrict__ gpb,
    const float* __restrict__ cbv, float* __restrict__ mask_out) {
    __shared__ __align__(16) float pt[32][65];
    int blk = blockIdx.x;            // row*12 + seg
    int row = blk / 12, seg = blk % 12;
    int b = row / LSEQ, i = row % LSEQ;
    int t = threadIdx.x;             // 0..63
    int pl = t & 31, hq = t >> 5;
    int j0 = seg * 32;
    float piv = pi[row * 64 + t];
    const float* pjb = pj + ((size_t)b * LSEQ + j0) * 64;
#pragma unroll 8
    for (int j = 0; j < 32; ++j) {
        int r = j0 + j - i; r = r < -32 ? -32 : (r > 32 ? 32 : r); r += 32;
        pt[j][t] = piv + pjb[j * 64 + t] + rel_emb[r * 64 + t];
    }
    __syncthreads();
    // mask: dot = rsqrt(var) * sum(d * g*pbs) + sum(b*pbs)
    float vv[32];
    float sv = 0.0f;
#pragma unroll
    for (int c = 0; c < 32; ++c) { vv[c] = pt[pl][hq * 32 + c]; sv += vv[c]; }
    sv += __shfl_xor(sv, 32);
    float mean = sv * (1.0f / PDIM);
    float sd2 = 0.0f, sdg = 0.0f;
#pragma unroll
    for (int c = 0; c < 32; ++c) {
        float d = vv[c] - mean;
        sd2 = fmaf(d, d, sd2);
        sdg = fmaf(d, gpb[hq * 32 + c], sdg);
    }
    sd2 += __shfl_xor(sd2, 32);
    sdg += __shfl_xor(sdg, 32);
    float rsv = rsqrtf(sd2 * (1.0f / PDIM) + 1e-5f);
    float dot = rsv * sdg + cbv[0];
    if (hq == 0)
        atomicAdd(mask_out + i * LSEQ + j0 + pl, dot * (1.0f / (BATCH * NHEAD)));
}

// prep: fold LN g/b into W1 (b1p = b1 + bb@W1), split all pair-MLP weights into
// bf16 hi/lo, stored TRANSPOSED [out][k] for direct 16B MFMA A-frag loads.
__global__ void k_prep(const float* __restrict__ pu_ln_g, const float* __restrict__ pu_ln_b,
                       const float* __restrict__ pu_w1, const float* __restrict__ pu_b1,
                       const float* __restrict__ pu_w2,
                       const float* __restrict__ dh_ln_g, const float* __restrict__ dh_ln_b,
                       const float* __restrict__ dh_w1, const float* __restrict__ dh_b1,
                       const float* __restrict__ dh_w2,
                       unsigned short* __restrict__ w1hT, unsigned short* __restrict__ w1lT,
                       unsigned short* __restrict__ w2hT, unsigned short* __restrict__ w2lT,
                       float* __restrict__ b1p, float* __restrict__ w2c) {
    int i = blockIdx.x;              // 0..4
    int c = threadIdx.x;             // 0..63 = output row of transposed arrays
    const float *g, *bb, *w1, *b1, *w2;
    int w2s;
    if (i < 4) { g = pu_ln_g + i * 64; bb = pu_ln_b + i * 64; w1 = pu_w1 + i * 4096;
                 b1 = pu_b1 + i * 64; w2 = pu_w2 + i * 4096; w2s = 64; }
    else       { g = dh_ln_g; bb = dh_ln_b; w1 = dh_w1; b1 = dh_b1; w2 = dh_w2; w2s = 65; }
    float accb = b1[c];
    for (int k = 0; k < 64; ++k) {
        float wv = w1[k * 64 + c];
        accb += bb[k] * wv;
        unsigned short h, l;
        split_bf(g[k] * wv, h, l);                 // W1'[k][c] stored at [c][k]
        w1hT[i * 4096 + c * 64 + k] = h;
        w1lT[i * 4096 + c * 64 + k] = l;
        split_bf(w2[k * w2s + c], h, l);           // W2[k][c] stored at [c][k]
        w2hT[i * 4096 + c * 64 + k] = h;
        w2lT[i * 4096 + c * 64 + k] = l;
    }
    b1p[i * 64 + c] = accb;
    if (i == 4) w2c[c] = dh_w2[c * 65 + 64];
}

// prep for fused mask: gp[li][c] = ln_pair_g[li][c] * pbs[c],
// cb[li] = sum_c ln_pair_b[li][c]*pbs[c], pbs[c] = sum_h pb_w[li][c][h]. li=0..3.
__global__ void k_maskprep(const float* __restrict__ g, const float* __restrict__ bb,
                           const float* __restrict__ pbw, float* __restrict__ gp,
                           float* __restrict__ cb) {
    int li = blockIdx.x;             // layer 0..3
    int c = threadIdx.x;             // 0..63 (one wave)
    const float* pw = pbw + li * PDIM * NHEAD;
    float pbs = pw[c * 4] + pw[c * 4 + 1] + pw[c * 4 + 2] + pw[c * 4 + 3];
    gp[li * 64 + c] = g[li * 64 + c] * pbs;
    float s = wsum(bb[li * 64 + c] * pbs);
    if (c == 0) cb[li] = s;
}

// prep: split+transpose seq weights to bf16 hi/lo [n][k] via 64x64 LDS tiles.
// src: [K][N] row-major, per-layer stride sstride; dst: [N][K], stride dstride.
__global__ void k_split_T(const float* __restrict__ src, unsigned short* __restrict__ dh,
                          unsigned short* __restrict__ dl, int K, int N,
                          int tiles_k, int tiles_n, size_t sstride, size_t dstride) {
    __shared__ float lds[64][65];
    int bid = blockIdx.x;
    int tpl = tiles_k * tiles_n;
    int layer = bid / tpl;
    int rest = bid % tpl;
    int kt = rest / tiles_n, nt = rest % tiles_n;
    const float* s = src + layer * sstride;
    int t = threadIdx.x, c = t & 63, r0 = t >> 6;
    for (int r = r0; r < 64; r += 4)
        lds[r][c] = s[(size_t)(kt * 64 + r) * N + nt * 64 + c];
    __syncthreads();
    unsigned short* oh = dh + layer * dstride;
    unsigned short* ol = dl + layer * dstride;
    for (int r = r0; r < 64; r += 4) {
        float v = lds[c][r];                       // src[kt*64+c][nt*64+r]
        unsigned short h, l;
        split_bf(v, h, l);
        size_t o = (size_t)(nt * 64 + r) * K + kt * 64 + c;
        oh[o] = h;
        ol[o] = l;
    }
}

// ============ generic MFMA seq GEMM ============
// OUT[m][n] = epi( X[m][:]@W + bias[n] + (R?R[m][n]:0) ), M=768 rows.
// W pre-split bf16 hi/lo transposed [n][k]. ONE 32x32 wave-tile per 64-thread
// block; grid = #tiles (spreads small GEMMs across all CUs).
template<bool GELU>
__global__ void __launch_bounds__(64) k_gemm(
    const float* __restrict__ X, const unsigned short* __restrict__ wTh,
    const unsigned short* __restrict__ wTl, const float* __restrict__ bias,
    const float* __restrict__ R, float* __restrict__ OUT, int K, int N) {
    int idx = blockIdx.x;
    int lane = threadIdx.x & 63;
    int pl = lane & 31, hq = lane >> 5;
    int ntiles = N >> 5;
    int mt = idx / ntiles, nt = idx % ntiles;
    const float* xr = X + (size_t)(mt * 32 + pl) * K + 8 * hq;
    const unsigned short* bh = wTh + (size_t)(nt * 32 + pl) * K + 8 * hq;
    const unsigned short* bl = wTl + (size_t)(nt * 32 + pl) * K + 8 * hq;
    int n = nt * 32 + pl;
    float bv = bias[n];
    f32x16 acc;
#pragma unroll
    for (int r = 0; r < 16; ++r) {
        int mr = mt * 32 + (r & 3) + 8 * (r >> 2) + 4 * hq;
        acc[r] = bv + (R ? R[(size_t)mr * N + n] : 0.0f);
    }
#pragma unroll 4
    for (int s = 0; s < K; s += 16) {
        const f32x4* x4 = (const f32x4*)(xr + s);
        f32x4 xa = x4[0], xb = x4[1];
        float xv[8];
#pragma unroll
        for (int j = 0; j < 4; ++j) { xv[j] = xa[j]; xv[4 + j] = xb[j]; }
        u32x4 ah, al;
        pack8(xv, ah, al);
        bf16x8 bhv = *(const bf16x8*)(bh + s);
        bf16x8 blv = *(const bf16x8*)(bl + s);
        acc = MFMA32(as_bf(ah), bhv, acc);
        acc = MFMA32(as_bf(al), bhv, acc);
        acc = MFMA32(as_bf(ah), blv, acc);
    }
#pragma unroll
    for (int r = 0; r < 16; ++r) {
        int mr = mt * 32 + (r & 3) + 8 * (r >> 2) + 4 * hq;
        float v = acc[r];
        OUT[(size_t)mr * N + n] = GELU ? gelu_erf(v) : v;
    }
}

// seq layernorm: one row per block
__global__ void k_ln_seq(const float* __restrict__ h, const float* __restrict__ g,
                         const float* __restrict__ b, float* __restrict__ out) {
    __shared__ float red[8];
    int row = blockIdx.x;
    int t = threadIdx.x;
    int w = t >> 6, lane = t & 63;
    float v = h[row * HD + t];
    float s = wsum(v);
    if (lane == 0) red[w] = s;
    __syncthreads();
    float mean = (red[0] + red[1] + red[2] + red[3]) * (1.0f / HD);
    float d = v - mean;
    float q = wsum(d * d);
    if (lane == 0) red[4 + w] = q;
    __syncthreads();
    float var = (red[4] + red[5] + red[6] + red[7]) * (1.0f / HD);
    out[row * HD + t] = d * rsqrtf(var + 1e-5f) * g[t] + b[t];
}

// attention for one (b, nh, l) per block
__global__ void k_attn(const float* __restrict__ qkv, const float* __restrict__ mask,
                       float* __restrict__ o) {
    __shared__ __align__(16) float qs[64];
    __shared__ float sc[LSEQ];
    __shared__ float red[8];
    __shared__ float op[4][64];
    int bid = blockIdx.x;
    int l = bid % LSEQ;
    int nh = (bid / LSEQ) & 3;
    int b = bid / (LSEQ * NHEAD);
    int t = threadIdx.x;
    int w = t >> 6, lane = t & 63;
    const float* qbase = qkv + ((size_t)(b * LSEQ + l)) * 768 + nh * 64;
    if (t < 64) qs[t] = qbase[t];
    __syncthreads();
    float lmax = -1e30f;
    float myv[2];
#pragma unroll
    for (int it = 0; it < 2; ++it) {
        int m = t + it * 256;
        if (m < LSEQ) {
            const float* kb = qkv + ((size_t)(b * LSEQ + m)) * 768 + 256 + nh * 64;
            const float4* k4 = (const float4*)kb;
            const float4* q4 = (const float4*)qs;
            float acc = 0.0f;
#pragma unroll
            for (int a = 0; a < 16; ++a) {
                float4 kv = k4[a], qv = q4[a];
                acc += qv.x * kv.x + qv.y * kv.y + qv.z * kv.z + qv.w * kv.w;
            }
            float s = acc * 0.125f + mask[l * LSEQ + m];
            myv[it] = s;
            lmax = fmaxf(lmax, s);
        } else myv[it] = -1e30f;
    }
    float wm = wmax(lmax);
    if (lane == 0) red[w] = wm;
    __syncthreads();
    float gmax = fmaxf(fmaxf(red[0], red[1]), fmaxf(red[2], red[3]));
    float lsum = 0.0f;
#pragma unroll
    for (int it = 0; it < 2; ++it) {
        int m = t + it * 256;
        if (m < LSEQ) {
            float e = expf(myv[it] - gmax);
            sc[m] = e;
            lsum += e;
        }
    }
    float ws = wsum(lsum);
    if (lane == 0) red[4 + w] = ws;
    __syncthreads();
    float inv = 1.0f / (red[4] + red[5] + red[6] + red[7]);
    int d = t & 63, gq = t >> 6;
    float part = 0.0f;
    for (int m = gq * 96; m < (gq + 1) * 96; ++m)
        part += sc[m] * qkv[((size_t)(b * LSEQ + m)) * 768 + 512 + nh * 64 + d];
    op[gq][d] = part;
    __syncthreads();
    if (t < 64) {
        float ov = (op[0][t] + op[1][t] + op[2][t] + op[3][t]) * inv;
        o[((size_t)(b * LSEQ + l)) * HD + nh * 64 + t] = ov;
    }
}

// ============ MFMA pair-update: 2-phase LDS weights, early residual ============
// Block = 256 threads = 4 waves, 128 j. MODE 0: layer-0 (residual = pair-init
// computed on the fly, pair never pre-initialized in HBM) + fused next mask.
// MODE 1: mid layer (residual read) + fused next mask. MODE 2: last layer,
// fused distogram head (register reorder, dw re-stage, smem output tile).
// __launch_bounds__(256,4) pins VGPR <= 128 (4 waves/SIMD cap preserved).
template<int MODE>
__global__ void __launch_bounds__(256, 4) k_pair_upd(
    const float* __restrict__ ojc,   // centered oj         (B,L,64)
    const float* __restrict__ oic,   // centered oi+outer_b (B,L,64)
    const unsigned short* __restrict__ w1hT, const unsigned short* __restrict__ w1lT,
    const float* __restrict__ b1p,
    const unsigned short* __restrict__ w2hT, const unsigned short* __restrict__ w2lT,
    const float* __restrict__ b2, float* __restrict__ pair,
    const float* __restrict__ gpb, const float* __restrict__ cbv,
    float* __restrict__ mask_out,
    const float* __restrict__ ipi, const float* __restrict__ ipj,
    const float* __restrict__ rel,
    const unsigned short* __restrict__ dw1h, const unsigned short* __restrict__ dw1l,
    const float* __restrict__ db1p,
    const unsigned short* __restrict__ dw2h, const unsigned short* __restrict__ dw2l,
    const float* __restrict__ w2c, const float* __restrict__ db2,
    float* __restrict__ outg) {
    constexpr bool DIST = (MODE == 2);
    __shared__ __align__(16) char smem[DIST ? 33344 : 17472];
    short (*lw)[64][68] = (short (*)[64][68])smem;   // [2][64][68] hi|lo, padded
    int blk = blockIdx.x;            // row*3 + seg
    int row = blk / 3, seg = blk % 3;
    int b = row / LSEQ;
    int t = threadIdx.x;
    int wave = t >> 6, lane = t & 63;
    int pl = lane & 31, hq = lane >> 5;
    int jj = wave * 32 + pl;         // 0..127 within segment
    int p = seg * 128 + jj;
    const float* ojr = ojc + ((size_t)b * LSEQ + p) * 64;
    const float* oir = oic + (size_t)row * 64;
    float* prp = pair + ((size_t)row * LSEQ + p) * 64;

    // ---- EARLY residual: issue at kernel entry, consumed after MFMA1 ----
    f32x4 r0[4], r1[4];
    if constexpr (MODE == 0) {
        int l = row % LSEQ;
        int rr_ = p - l; rr_ = rr_ < -32 ? -32 : (rr_ > 32 ? 32 : rr_); rr_ += 32;
        const f32x4* i4 = (const f32x4*)(ipi + (size_t)row * 64);
        const f32x4* j4 = (const f32x4*)(ipj + ((size_t)b * LSEQ + p) * 64);
        const f32x4* e4 = (const f32x4*)(rel + rr_ * 64);
#pragma unroll
        for (int g = 0; g < 4; ++g) {
            r0[g] = i4[2 * g + hq] + j4[2 * g + hq] + e4[2 * g + hq];
            r1[g] = i4[8 + 2 * g + hq] + j4[8 + 2 * g + hq] + e4[8 + 2 * g + hq];
        }
    } else {
        const f32x4* pr4 = (const f32x4*)prp;
#pragma unroll
        for (int g = 0; g < 4; ++g) {
            r0[g] = pr4[2 * g + hq];
            r1[g] = pr4[8 + 2 * g + hq];
        }
    }

    // ---- v = oj + oi, vectorized ----
    float v[32];
    {
        const f32x4* a4 = (const f32x4*)ojr;
        const f32x4* c4 = (const f32x4*)oir;
#pragma unroll
        for (int s = 0; s < 4; ++s) {
            f32x4 a = a4[4 * s + 2 * hq], aa = a4[4 * s + 2 * hq + 1];
            f32x4 c = c4[4 * s + 2 * hq], cc = c4[4 * s + 2 * hq + 1];
#pragma unroll
            for (int j = 0; j < 4; ++j) {
                v[8 * s + j] = a[j] + c[j];
                v[8 * s + 4 + j] = aa[j] + cc[j];
            }
        }
    }
    stage_w(lw, t, w1hT, w1lT);

    // LN (mean removed upstream) + bf16 hi/lo pack via cvt_pk
    float ss = 0.0f;
#pragma unroll
    for (int i = 0; i < 32; ++i) ss = fmaf(v[i], v[i], ss);
    ss += __shfl_xor(ss, 32);
    float rs = rsqrtf(ss * (1.0f / PDIM) + 1e-5f);
#pragma unroll
    for (int i = 0; i < 32; ++i) v[i] *= rs;
    u32x4 zh[4], zl[4];
#pragma unroll
    for (int s = 0; s < 4; ++s) pack8(v + 8 * s, zh[s], zl[s]);

    const f32x4* b14 = (const f32x4*)b1p;
    f32x4 bi0[4], bi1[4];
#pragma unroll
    for (int g = 0; g < 4; ++g) { bi0[g] = b14[2 * g + hq]; bi1[g] = b14[8 + 2 * g + hq]; }

    __syncthreads();   // w1 staged

    f32x16 acc0, acc1;
#pragma unroll
    for (int r = 0; r < 16; ++r) {
        acc0[r] = bi0[r >> 2][r & 3];
        acc1[r] = bi1[r >> 2][r & 3];
    }
#pragma unroll
    for (int s = 0; s < 4; ++s) {
        int ko = 16 * s + 8 * hq;
        bf16x8 a0h = ld8(&lw[0][pl][ko]);
        bf16x8 a0l = ld8(&lw[1][pl][ko]);
        bf16x8 a1h = ld8(&lw[0][32 + pl][ko]);
        bf16x8 a1l = ld8(&lw[1][32 + pl][ko]);
        bf16x8 zhs = as_bf(zh[s]), zls = as_bf(zl[s]);
        acc0 = MFMA32(a0h, zhs, acc0);
        acc0 = MFMA32(a0h, zls, acc0);
        acc0 = MFMA32(a0l, zhs, acc0);
        acc1 = MFMA32(a1h, zhs, acc1);
        acc1 = MFMA32(a1h, zls, acc1);
        acc1 = MFMA32(a1l, zhs, acc1);
    }
    __syncthreads();   // all waves done reading w1
    stage_w(lw, t, w2hT, w2lT);  // load latency hides under gelu below

    float u0[16], u1[16];
#pragma unroll
    for (int r = 0; r < 16; ++r) { u0[r] = gelu_erf(acc0[r]); u1[r] = gelu_erf(acc1[r]); }

    // bias2 broadcast loads (L2-hot)
    f32x4 q0[4], q1[4];
    {
        const f32x4* b24 = (const f32x4*)b2;
#pragma unroll
        for (int g = 0; g < 4; ++g) {
            q0[g] = b24[2 * g + hq];
            q1[g] = b24[8 + 2 * g + hq];
        }
    }

    float rA0[4], rB0[4], rA1[4], rB1[4];
#pragma unroll
    for (int i = 0; i < 4; ++i) {
        rA0[i] = __shfl_xor(hq ? u0[i] : u0[4 + i], 32);
        rB0[i] = __shfl_xor(hq ? u0[8 + i] : u0[12 + i], 32);
        rA1[i] = __shfl_xor(hq ? u1[i] : u1[4 + i], 32);
        rB1[i] = __shfl_xor(hq ? u1[8 + i] : u1[12 + i], 32);
    }
    u32x4 uh[4], ul[4];
#pragma unroll
    for (int s = 0; s < 4; ++s) {
        int tt = s >> 1, q = s & 1;
        float fg[8];
#pragma unroll
        for (int i = 0; i < 4; ++i) {
            float own_f = q ? (tt ? u1[8 + i] : u0[8 + i]) : (tt ? u1[i] : u0[i]);
            float own_s = q ? (tt ? u1[12 + i] : u0[12 + i]) : (tt ? u1[4 + i] : u0[4 + i]);
            float rcv   = q ? (tt ? rB1[i] : rB0[i]) : (tt ? rA1[i] : rA0[i]);
            fg[i]     = hq ? rcv : own_f;
            fg[4 + i] = hq ? own_s : rcv;
        }
        pack8(fg, uh[s], ul[s]);
    }

    __syncthreads();   // w2 staged

    f32x16 c0, c1;
#pragma unroll
    for (int r = 0; r < 16; ++r) {
        int g = r >> 2, i = r & 3;
        c0[r] = q0[g][i] + r0[g][i];
        c1[r] = q1[g][i] + r1[g][i];
    }
#pragma unroll
    for (int s = 0; s < 4; ++s) {
        int ko = 16 * s + 8 * hq;
        bf16x8 a0h = ld8(&lw[0][pl][ko]);
        bf16x8 a0l = ld8(&lw[1][pl][ko]);
        bf16x8 a1h = ld8(&lw[0][32 + pl][ko]);
        bf16x8 a1l = ld8(&lw[1][32 + pl][ko]);
        bf16x8 uhs = as_bf(uh[s]), uls = as_bf(ul[s]);
        c0 = MFMA32(a0h, uhs, c0);
        c0 = MFMA32(a0h, uls, c0);
        c0 = MFMA32(a0l, uhs, c0);
        c1 = MFMA32(a1h, uhs, c1);
        c1 = MFMA32(a1h, uls, c1);
        c1 = MFMA32(a1l, uhs, c1);
    }

    if constexpr (!DIST) {
        // fused mask for next layer: LN(final pair) . pbsum, mean over b via atomics
        const f32x4* gp4 = (const f32x4*)gpb;
        f32x4 gp0[4], gp1[4];
#pragma unroll
        for (int g = 0; g < 4; ++g) { gp0[g] = gp4[2 * g + hq]; gp1[g] = gp4[8 + 2 * g + hq]; }
        float sv = 0.0f;
#pragma unroll
        for (int r = 0; r < 16; ++r) sv += c0[r] + c1[r];
        sv += __shfl_xor(sv, 32);
        float mean = sv * (1.0f / PDIM);
        float sd2 = 0.0f, sdg = 0.0f;
#pragma unroll 4
        for (int r = 0; r < 16; ++r) {
            int g = r >> 2, i = r & 3;
            float d0 = c0[r] - mean, d1 = c1[r] - mean;
            sd2 = fmaf(d0, d0, sd2);
            sd2 = fmaf(d1, d1, sd2);
            sdg = fmaf(d0, gp0[g][i], sdg);
            sdg = fmaf(d1, gp1[g][i], sdg);
        }
        sd2 += __shfl_xor(sd2, 32);
        sdg += __shfl_xor(sdg, 32);
        float rsv = rsqrtf(sd2 * (1.0f / PDIM) + 1e-5f);
        float dot = rsv * sdg + cbv[0];
        if (hq == 0)
            atomicAdd(mask_out + (row % LSEQ) * LSEQ + p, dot * (1.0f / (BATCH * NHEAD)));
        // store updated pair: lane-private float4 x8
        f32x4* pw4 = (f32x4*)prp;
#pragma unroll
        for (int g = 0; g < 4; ++g) {
            f32x4 s0, s1;
#pragma unroll
            for (int i = 0; i < 4; ++i) { s0[i] = c0[4 * g + i]; s1[i] = c1[4 * g + i]; }
            pw4[2 * g + hq] = s0;
            pw4[8 + 2 * g + hq] = s1;
        }
    } else {
        // ---- fused distogram head; fragment->k-order reorder in registers ----
        // partner lane (xor 32) holds exactly the interleaved 4-channel groups:
        float ra[4], rb[4], rc[4], rd[4];
#pragma unroll
        for (int i = 0; i < 4; ++i) {
            ra[i] = __shfl_xor(hq ? c0[i] : c0[4 + i], 32);
            rb[i] = __shfl_xor(hq ? c0[8 + i] : c0[12 + i], 32);
            rc[i] = __shfl_xor(hq ? c1[i] : c1[4 + i], 32);
            rd[i] = __shfl_xor(hq ? c1[8 + i] : c1[12 + i], 32);
        }
        float v2[32];
#pragma unroll
        for (int i = 0; i < 4; ++i) {
            v2[i]      = hq ? ra[i] : c0[i];
            v2[4 + i]  = hq ? c0[4 + i] : ra[i];
            v2[8 + i]  = hq ? rb[i] : c0[8 + i];
            v2[12 + i] = hq ? c0[12 + i] : rb[i];
            v2[16 + i] = hq ? rc[i] : c1[i];
            v2[20 + i] = hq ? c1[4 + i] : rc[i];
            v2[24 + i] = hq ? rd[i] : c1[8 + i];
            v2[28 + i] = hq ? c1[12 + i] : rd[i];
        }
        __syncthreads();   // all waves done reading pu w2
        stage_w(lw, t, dw1h, dw1l);

        float sm = 0.0f;
#pragma unroll
        for (int i = 0; i < 32; ++i) sm += v2[i];
        sm += __shfl_xor(sm, 32);
        float mean = sm * (1.0f / PDIM);
        float ss2 = 0.0f;
#pragma unroll
        for (int i = 0; i < 32; ++i) { v2[i] -= mean; ss2 = fmaf(v2[i], v2[i], ss2); }
        ss2 += __shfl_xor(ss2, 32);
        float rs2 = rsqrtf(ss2 * (1.0f / PDIM) + 1e-5f);
#pragma unroll
        for (int i = 0; i < 32; ++i) v2[i] *= rs2;
#pragma unroll
        for (int s = 0; s < 4; ++s) pack8(v2 + 8 * s, zh[s], zl[s]);

        const f32x4* d14 = (const f32x4*)db1p;
        const f32x4* d24 = (const f32x4*)db2;
        const f32x4* wc4 = (const f32x4*)w2c;
        f32x4 di0[4], di1[4], e0[4], e1[4], wc0[4], wc1[4];
#pragma unroll
        for (int g = 0; g < 4; ++g) {
            di0[g] = d14[2 * g + hq]; di1[g] = d14[8 + 2 * g + hq];
            e0[g] = d24[2 * g + hq];  e1[g] = d24[8 + 2 * g + hq];
            wc0[g] = wc4[2 * g + hq]; wc1[g] = wc4[8 + 2 * g + hq];
        }
        __syncthreads();   // dw1 staged

#pragma unroll
        for (int r = 0; r < 16; ++r) {
            acc0[r] = di0[r >> 2][r & 3];
            acc1[r] = di1[r >> 2][r & 3];
        }
#pragma unroll
        for (int s = 0; s < 4; ++s) {
            int ko = 16 * s + 8 * hq;
            bf16x8 a0h = ld8(&lw[0][pl][ko]);
            bf16x8 a0l = ld8(&lw[1][pl][ko]);
            bf16x8 a1h = ld8(&lw[0][32 + pl][ko]);
            bf16x8 a1l = ld8(&lw[1][32 + pl][ko]);
            bf16x8 zhs = as_bf(zh[s]), zls = as_bf(zl[s]);
            acc0 = MFMA32(a0h, zhs, acc0);
            acc0 = MFMA32(a0h, zls, acc0);
            acc0 = MFMA32(a0l, zhs, acc0);
            acc1 = MFMA32(a1h, zhs, acc1);
            acc1 = MFMA32(a1h, zls, acc1);
            acc1 = MFMA32(a1l, zhs, acc1);
        }
        __syncthreads();   // done reading dw1
        stage_w(lw, t, dw2h, dw2l);

        float p64 = 0.0f;
#pragma unroll
        for (int r = 0; r < 16; ++r) {
            int g = r >> 2, i = r & 3;
            u0[r] = gelu_erf(acc0[r]);
            u1[r] = gelu_erf(acc1[r]);
            p64 = fmaf(u0[r], wc0[g][i], p64);
            p64 = fmaf(u1[r], wc1[g][i], p64);
        }
        p64 += __shfl_xor(p64, 32);
#pragma unroll
        for (int i = 0; i < 4; ++i) {
            rA0[i] = __shfl_xor(hq ? u0[i] : u0[4 + i], 32);
            rB0[i] = __shfl_xor(hq ? u0[8 + i] : u0[12 + i], 32);
            rA1[i] = __shfl_xor(hq ? u1[i] : u1[4 + i], 32);
            rB1[i] = __shfl_xor(hq ? u1[8 + i] : u1[12 + i], 32);
        }
#pragma unroll
        for (int s = 0; s < 4; ++s) {
            int tt = s >> 1, q = s & 1;
            float fg[8];
#pragma unroll
            for (int i = 0; i < 4; ++i) {
                float own_f = q ? (tt ? u1[8 + i] : u0[8 + i]) : (tt ? u1[i] : u0[i]);
                float own_s = q ? (tt ? u1[12 + i] : u0[12 + i]) : (tt ? u1[4 + i] : u0[4 + i]);
                float rcv   = q ? (tt ? rB1[i] : rB0[i]) : (tt ? rA1[i] : rA0[i]);
                fg[i]     = hq ? rcv : own_f;
                fg[4 + i] = hq ? own_s : rcv;
            }
            pack8(fg, uh[s], ul[s]);
        }
        __syncthreads();   // dw2 staged

#pragma unroll
        for (int r = 0; r < 16; ++r) {
            c0[r] = e0[r >> 2][r & 3];
            c1[r] = e1[r >> 2][r & 3];
        }
#pragma unroll
        for (int s = 0; s < 4; ++s) {
            int ko = 16 * s + 8 * hq;
            bf16x8 a0h = ld8(&lw[0][pl][ko]);
            bf16x8 a0l = ld8(&lw[1][pl][ko]);
            bf16x8 a1h = ld8(&lw[0][32 + pl][ko]);
            bf16x8 a1l = ld8(&lw[1][32 + pl][ko]);
            bf16x8 uhs = as_bf(uh[s]), uls = as_bf(ul[s]);
            c0 = MFMA32(a0h, uhs, c0);
            c0 = MFMA32(a0h, uls, c0);
            c0 = MFMA32(a0l, uhs, c0);
            c1 = MFMA32(a1h, uhs, c1);
            c1 = MFMA32(a1h, uls, c1);
            c1 = MFMA32(a1l, uhs, c1);
        }
        __syncthreads();   // lw dead everywhere -> reuse smem as output tile
        float (*pt)[65] = (float (*)[65])smem;
#pragma unroll
        for (int r = 0; r < 16; ++r) {
            int rr = (r & 3) + 8 * (r >> 2) + 4 * hq;
            pt[jj][rr] = c0[r];
            pt[jj][32 + rr] = c1[r];
        }
        if (hq == 0) pt[jj][64] = p64 + db2[64];
        __syncthreads();
        float4* dst = (float4*)(outg + ((size_t)row * LSEQ + seg * 128) * NBINS);
        const float4* srcl = (const float4*)&pt[0][0];
        for (int n = t; n < 128 * NBINS / 4; n += 256) dst[n] = srcl[n];
    }
}

// out = (out + out^T(1,2)) / 2, in place.  One 16x16 (l,m) tile pair per block
// (upper triangle incl diagonal); lanes run along the contiguous 65-bin axis.
__global__ void k_sym(float* __restrict__ out) {
    int u = blockIdx.x;
    int b = 0;
    if (u >= NTRI) { b = 1; u -= NTRI; }
    int lt = 0, rem = NTT;
    while (u >= rem) { u -= rem; ++lt; --rem; }
    int mt = lt + u;
    int t = threadIdx.x;
    int g = t >> 6, lane = t & 63;
    float* ob = out + (size_t)b * LSEQ * LSEQ * NBINS;
    for (int e = g; e < 256; e += 4) {
        int i = e >> 4, j = e & 15;
        if (lt == mt && j < i) continue;
        size_t ia = ((size_t)(lt * 16 + i) * LSEQ + (mt * 16 + j)) * NBINS;
        size_t ib = ((size_t)(mt * 16 + j) * LSEQ + (lt * 16 + i)) * NBINS;
        for (int k = lane; k < NBINS; k += 64) {
            float a = ob[ia + k], c = ob[ib + k];
            float vv = 0.5f * (a + c);
            ob[ia + k] = vv;
            if (ia != ib) ob[ib + k] = vv;
        }
    }
}

extern "C" void kernel_launch(void* const* d_in, const int* in_sizes, int n_in,
                              void* d_out, int out_size, void* d_ws, size_t ws_size,
                              hipStream_t stream) {
    const float* x        = (const float*)d_in[0];
    const float* rp_w     = (const float*)d_in[1];
    const float* rp_b     = (const float*)d_in[2];
    const float* pos      = (const float*)d_in[3];
    const float* pii_w    = (const float*)d_in[4];
    const float* pii_b    = (const float*)d_in[5];
    const float* pij_w    = (const float*)d_in[6];
    const float* pij_b    = (const float*)d_in[7];
    const float* rel_emb  = (const float*)d_in[8];
    const float* ln_seq_g = (const float*)d_in[9];
    const float* ln_seq_b = (const float*)d_in[10];
    const float* ln_pair_g= (const float*)d_in[11];
    const float* ln_pair_b= (const float*)d_in[12];
    const float* pb_w     = (const float*)d_in[13];
    const float* in_w     = (const float*)d_in[14];
    const float* in_b     = (const float*)d_in[15];
    const float* out_w    = (const float*)d_in[16];
    const float* out_b    = (const float*)d_in[17];
    const float* ff_ln_g  = (const float*)d_in[18];
    const float* ff_ln_b  = (const float*)d_in[19];
    const float* ff_w1    = (const float*)d_in[20];
    const float* ff_b1    = (const float*)d_in[21];
    const float* ff_w2    = (const float*)d_in[22];
    const float* ff_b2    = (const float*)d_in[23];
    const float* pu_ln_g  = (const float*)d_in[24];
    const float* pu_ln_b  = (const float*)d_in[25];
    const float* pu_w1    = (const float*)d_in[26];
    const float* pu_b1    = (const float*)d_in[27];
    const float* pu_w2    = (const float*)d_in[28];
    const float* pu_b2    = (const float*)d_in[29];
    const float* outer_w  = (const float*)d_in[30];
    const float* outer_b  = (const float*)d_in[31];
    const float* dh_ln_g  = (const float*)d_in[32];
    const float* dh_ln_b  = (const float*)d_in[33];
    const float* dh_w1    = (const float*)d_in[34];
    const float* dh_b1    = (const float*)d_in[35];
    const float* dh_w2    = (const float*)d_in[36];
    const float* dh_b2    = (const float*)d_in[37];
    float* outp = (float*)d_out;

    float* W = (float*)d_ws;
    float* h    = W;  W += BATCH * LSEQ * HD;
    float* sn   = W;  W += BATCH * LSEQ * HD;
    float* qkv  = W;  W += BATCH * LSEQ * 3 * HD;
    float* ob   = W;  W += BATCH * LSEQ * HD;
    float* mid  = W;  W += BATCH * LSEQ * 4 * HD;
    float* maskA= W;  W += LSEQ * LSEQ;
    float* maskB= W;  W += LSEQ * LSEQ;
    float* poi  = W;  W += BATCH * LSEQ * PDIM;
    float* poj  = W;  W += BATCH * LSEQ * PDIM;
    float* poi0 = W;  W += BATCH * LSEQ * PDIM;   // pair-init projections (kept)
    float* poj0 = W;  W += BATCH * LSEQ * PDIM;
    float* b1p  = W;  W += 5 * 64;
    float* w2c  = W;  W += 64;
    float* gpb  = W;  W += 4 * 64;
    float* cbv  = W;  W += 64;
    unsigned short* w1hT = (unsigned short*)W;  W += 5 * 2048;
    unsigned short* w1lT = (unsigned short*)W;  W += 5 * 2048;
    unsigned short* w2hT = (unsigned short*)W;  W += 5 * 2048;
    unsigned short* w2lT = (unsigned short*)W;  W += 5 * 2048;
    // seq-GEMM split/transposed weights (bf16 hi/lo), per-layer strides in elems
    unsigned short* qwT_h = (unsigned short*)W;  W += 4 * 196608 / 2;
    unsigned short* qwT_l = (unsigned short*)W;  W += 4 * 196608 / 2;
    unsigned short* owT_h = (unsigned short*)W;  W += 4 * 65536 / 2;
    unsigned short* owT_l = (unsigned short*)W;  W += 4 * 65536 / 2;
    unsigned short* f1T_h = (unsigned short*)W;  W += 4 * 262144 / 2;
    unsigned short* f1T_l = (unsigned short*)W;  W += 4 * 262144 / 2;
    unsigned short* f2T_h = (unsigned short*)W;  W += 4 * 262144 / 2;
    unsigned short* f2T_l = (unsigned short*)W;  W += 4 * 262144 / 2;
    float* pair = W;  W += (size_t)BATCH * LSEQ * LSEQ * PDIM;

    const int rows = BATCH * LSEQ;   // 768

    k_prep<<<5, 64, 0, stream>>>(pu_ln_g, pu_ln_b, pu_w1, pu_b1, pu_w2,
                                 dh_ln_g, dh_ln_b, dh_w1, dh_b1, dh_w2,
                                 w1hT, w1lT, w2hT, w2lT, b1p, w2c);
    k_maskprep<<<4, 64, 0, stream>>>(ln_pair_g, ln_pair_b, pb_w, gpb, cbv);
    k_split_T<<<4 * 4 * 12, 256, 0, stream>>>(in_w,  qwT_h, qwT_l, 256, 768,  4, 12, 196608, 196608);
    k_split_T<<<4 * 4 * 4,  256, 0, stream>>>(out_w, owT_h, owT_l, 256, 256,  4, 4,  65536,  65536);
    k_split_T<<<4 * 4 * 16, 256, 0, stream>>>(ff_w1, f1T_h, f1T_l, 256, 1024, 4, 16, 262144, 262144);
    k_split_T<<<4 * 16 * 4, 256, 0, stream>>>(ff_w2, f2T_h, f2T_l, 1024, 256, 16, 4, 262144, 262144);
    k_h_init<<<rows, 256, 0, stream>>>(x, rp_w, rp_b, pos, h);
    k_proj2<<<rows, 128, 0, stream>>>(h, pii_w, pij_w, pii_b, pij_b, 0, poi0, poj0);
    hipMemsetAsync(maskA, 0, LSEQ * LSEQ * sizeof(float), stream);
    // layer-0 mask from on-the-fly pair init (pair never written to HBM here)
    k_mask0<<<rows * 12, 64, 0, stream>>>(poi0, poj0, rel_emb, gpb, cbv, maskA);

    float* mcur = maskA;
    float* mnext = maskB;
    for (int i = 0; i < 4; ++i) {
        k_ln_seq<<<rows, 256, 0, stream>>>(h, ln_seq_g + i * HD, ln_seq_b + i * HD, sn);
        // qkv = sn @ in_w + in_b   (24 x 24 tiles, 1-wave blocks)
        k_gemm<false><<<576, 64, 0, stream>>>(sn, qwT_h + i * 196608, qwT_l + i * 196608,
                                              in_b + i * 768, nullptr, qkv, 256, 768);
        k_attn<<<BATCH * NHEAD * LSEQ, 256, 0, stream>>>(qkv, mcur, ob);
        // h += ob @ out_w + out_b  (24 x 8 tiles)
        k_gemm<false><<<192, 64, 0, stream>>>(ob, owT_h + i * 65536, owT_l + i * 65536,
                                              out_b + i * 256, h, h, 256, 256);
        k_ln_seq<<<rows, 256, 0, stream>>>(h, ff_ln_g + i * HD, ff_ln_b + i * HD, sn);
        // mid = gelu(sn @ ff_w1 + b1)  (24 x 32 tiles)
        k_gemm<true><<<768, 64, 0, stream>>>(sn, f1T_h + i * 262144, f1T_l + i * 262144,
                                             ff_b1 + i * 1024, nullptr, mid, 256, 1024);
        // h += mid @ ff_w2 + b2  (24 x 8 tiles)
        k_gemm<false><<<192, 64, 0, stream>>>(mid, f2T_h + i * 262144, f2T_l + i * 262144,
                                              ff_b2 + i * 256, h, h, 1024, 256);
        // centered oi+outer_b (poi) and centered oj (poj)
        k_proj2<<<rows, 128, 0, stream>>>(h, outer_w + i * 2 * HD * PDIM,
                                          outer_w + i * 2 * HD * PDIM + HD * PDIM,
                                          outer_b + i * PDIM, nullptr, 1, poi, poj);
        if (i == 0) {
            hipMemsetAsync(mnext, 0, LSEQ * LSEQ * sizeof(float), stream);
            // layer 0: residual = pair-init computed in-kernel (no pair read)
            k_pair_upd<0><<<rows * 3, 256, 0, stream>>>(
                poj, poi,
                w1hT, w1lT, b1p, w2hT, w2lT, pu_b2, pair,
                gpb + 64, cbv + 1, mnext, poi0, poj0, rel_emb,
                nullptr, nullptr, nullptr, nullptr, nullptr, nullptr, nullptr, nullptr);
            float* tmp = mcur; mcur = mnext; mnext = tmp;
        } else if (i < 3) {
            hipMemsetAsync(mnext, 0, LSEQ * LSEQ * sizeof(float), stream);
            k_pair_upd<1><<<rows * 3, 256, 0, stream>>>(
                poj, poi,
                w1hT + i * 4096, w1lT + i * 4096, b1p + i * 64,
                w2hT + i * 4096, w2lT + i * 4096, pu_b2 + i * PDIM, pair,
                gpb + (i + 1) * 64, cbv + (i + 1), mnext,
                nullptr, nullptr, nullptr,
                nullptr, nullptr, nullptr, nullptr, nullptr, nullptr, nullptr, nullptr);
            float* tmp = mcur; mcur = mnext; mnext = tmp;
        } else {
            // last layer: pair update fused with distogram head; pair never stored
            k_pair_upd<2><<<rows * 3, 256, 0, stream>>>(
                poj, poi,
                w1hT + 3 * 4096, w1lT + 3 * 4096, b1p + 3 * 64,
                w2hT + 3 * 4096, w2lT + 3 * 4096, pu_b2 + 3 * PDIM, pair,
                nullptr, nullptr, nullptr,
                nullptr, nullptr, nullptr,
                w1hT + 4 * 4096, w1lT + 4 * 4096, b1p + 4 * 64,
                w2hT + 4 * 4096, w2lT + 4 * 4096, w2c, dh_b2, outp);
        }
    }

    k_sym<<<2 * NTRI, 256, 0, stream>>>(outp);
}

// Round 10
// 1065.215 us; speedup vs baseline: 1.0748x; 1.0748x over previous
//
#include <hip/hip_runtime.h>
#include <math.h>

#define LSEQ 384
#define HD 256
#define PDIM 64
#define NHEAD 4
#define NBINS 65
#define BATCH 2
#define NTT (LSEQ / 16)
#define NTRI (NTT * (NTT + 1) / 2)

typedef __attribute__((ext_vector_type(8))) short bf16x8;
typedef __attribute__((ext_vector_type(16))) float f32x16;
typedef __attribute__((ext_vector_type(4))) float f32x4;
typedef __attribute__((ext_vector_type(4))) unsigned u32x4;
typedef __attribute__((ext_vector_type(4))) short s16x4;
#define MFMA32(a, b, c) __builtin_amdgcn_mfma_f32_32x32x16_bf16(a, b, c, 0, 0, 0)

// ---- DPP-based wave64 reductions (VALU pipe, not LDS) ----
template<int CTRL, int RMASK>
__device__ __forceinline__ float dpp_sum_step(float v) {
    int x = __builtin_amdgcn_update_dpp(0, __float_as_int(v), CTRL, RMASK, 0xf, true);
    return v + __int_as_float(x);
}
template<int CTRL, int RMASK>
__device__ __forceinline__ float dpp_max_step(float v) {
    int x = __builtin_amdgcn_update_dpp(__float_as_int(v), __float_as_int(v), CTRL, RMASK, 0xf, false);
    return fmaxf(v, __int_as_float(x));
}
__device__ __forceinline__ float wsum(float v) {
    v = dpp_sum_step<0x111, 0xf>(v);
    v = dpp_sum_step<0x112, 0xf>(v);
    v = dpp_sum_step<0x114, 0xf>(v);
    v = dpp_sum_step<0x118, 0xf>(v);
    v = dpp_sum_step<0x142, 0xa>(v);
    v = dpp_sum_step<0x143, 0xc>(v);
    return __int_as_float(__builtin_amdgcn_readlane(__float_as_int(v), 63));
}
__device__ __forceinline__ float wmax(float v) {
    v = dpp_max_step<0x111, 0xf>(v);
    v = dpp_max_step<0x112, 0xf>(v);
    v = dpp_max_step<0x114, 0xf>(v);
    v = dpp_max_step<0x118, 0xf>(v);
    v = dpp_max_step<0x142, 0xa>(v);
    v = dpp_max_step<0x143, 0xc>(v);
    return __int_as_float(__builtin_amdgcn_readlane(__float_as_int(v), 63));
}

// libm erf gelu — used in k_pair_upd. R9 evidence: any gelu variant that
// perturbs pair_upd's register allocation off 128 VGPR causes either an
// occupancy cliff (R5: 136 VGPR) or scratch spill (R9: forced 64 VGPR,
// +163MB spill traffic). libm erff allocates exactly 128 with zero spill.
__device__ __forceinline__ float gelu_erf(float x) {
    return 0.5f * x * (1.0f + erff(x * 0.70710678f));
}

// fast poly gelu (A&S 7.1.26, |erf err| <= 1.5e-7) on schedulable HIP
// intrinsics — used ONLY in k_gemm's epilogue (low register pressure,
// 1-wave kernel: no occupancy boundary to cross).
__device__ __forceinline__ float gelu_fast(float x) {
    float az = fabsf(x) * 0.70710678f;
    float t = __fdividef(1.0f, fmaf(0.3275911f, az, 1.0f));
    float p = fmaf(fmaf(fmaf(fmaf(1.061405429f, t, -1.453152027f), t,
                  1.421413741f), t, -0.284496736f), t, 0.254829592f) * t;
    float e = __expf(-az * az);
    float er = fmaf(-p, e, 1.0f);
    float s = x < 0.0f ? -er : er;
    return 0.5f * x * (1.0f + s);
}

// bf16 RNE conversion + error-compensated split: x ~= hi + lo
__device__ __forceinline__ unsigned short f2bf(float x) {
    unsigned u = __float_as_uint(x);
    unsigned r = (u + 0x7fff + ((u >> 16) & 1)) >> 16;
    return (unsigned short)r;
}
__device__ __forceinline__ float bf2f(unsigned short h) {
    return __uint_as_float(((unsigned)h) << 16);
}
__device__ __forceinline__ void split_bf(float x, unsigned short& h, unsigned short& l) {
    h = f2bf(x);
    l = f2bf(x - bf2f(h));
}

// HW packed f32->bf16 RNE (identical rounding to f2bf), 2 values per inst.
__device__ __forceinline__ unsigned cvt_pk_bf(float lo, float hi) {
    unsigned r;
    asm("v_cvt_pk_bf16_f32 %0, %1, %2" : "=v"(r) : "v"(lo), "v"(hi));
    return r;
}
// pack 8 floats -> hi bf16x8 + lo bf16x8 (error-compensated split), as u32x4
__device__ __forceinline__ void pack8(const float* v, u32x4& h, u32x4& l) {
#pragma unroll
    for (int j = 0; j < 4; ++j) {
        float a = v[2 * j], b = v[2 * j + 1];
        unsigned hp = cvt_pk_bf(a, b);
        float ra = a - __uint_as_float(hp << 16);
        float rb = b - __uint_as_float(hp & 0xffff0000u);
        h[j] = hp;
        l[j] = cvt_pk_bf(ra, rb);
    }
}
__device__ __forceinline__ bf16x8 as_bf(u32x4 x) {
    union { u32x4 u; bf16x8 b; } c; c.u = x; return c.b;
}
// load a bf16x8 fragment from LDS (8-byte aligned, padded-stride rows)
__device__ __forceinline__ bf16x8 ld8(const short* p) {
    s16x4 a = *(const s16x4*)p;
    s16x4 b = *(const s16x4*)(p + 4);
    bf16x8 r;
    r[0] = a[0]; r[1] = a[1]; r[2] = a[2]; r[3] = a[3];
    r[4] = b[0]; r[5] = b[1]; r[6] = b[2]; r[7] = b[3];
    return r;
}

// cooperative stage of one MLP's hi/lo weight pair into padded LDS
__device__ __forceinline__ void stage_w(short (*lw)[64][68], int t,
                                        const unsigned short* __restrict__ srcA,
                                        const unsigned short* __restrict__ srcB) {
    for (int idx = t; idx < 2048; idx += 256) {
        int rr2 = idx >> 5, cc2 = (idx & 31) * 2;
        *(unsigned*)&lw[0][rr2][cc2] = *(const unsigned*)(srcA + rr2 * 64 + cc2);
        *(unsigned*)&lw[1][rr2][cc2] = *(const unsigned*)(srcB + rr2 * 64 + cc2);
    }
}

// h[b,l,:] = x[b,l,:] @ rp_w + rp_b + pos[l,:]
__global__ void k_h_init(const float* __restrict__ x, const float* __restrict__ rp_w,
                         const float* __restrict__ rp_b, const float* __restrict__ pos,
                         float* __restrict__ h) {
    __shared__ float xs[48];
    int row = blockIdx.x;            // b*L + l
    int l = row % LSEQ;
    int t = threadIdx.x;
    if (t < 48) xs[t] = x[row * 48 + t];
    __syncthreads();
    float acc = rp_b[t] + pos[l * HD + t];
#pragma unroll 8
    for (int a = 0; a < 48; ++a) acc += xs[a] * rp_w[a * HD + t];
    h[row * HD + t] = acc;
}

// pA[row,:] = h[row,:] @ wA (+ bA);  pB[row,:] = h[row,:] @ wB (+ bB)
// center!=0: subtract per-row mean (LN-mean elimination downstream)
__global__ void k_proj2(const float* __restrict__ h, const float* __restrict__ wA,
                        const float* __restrict__ wB, const float* __restrict__ bA,
                        const float* __restrict__ bB, int center,
                        float* __restrict__ pA, float* __restrict__ pB) {
    __shared__ float hs[HD];
    int row = blockIdx.x;
    int t = threadIdx.x;
    hs[t] = h[row * HD + t];
    hs[t + 128] = h[row * HD + t + 128];
    __syncthreads();
    int col = t & 63;
    const float* w = (t < 64) ? wA : wB;
    const float* bias = (t < 64) ? bA : bB;
    float acc = bias ? bias[col] : 0.0f;
#pragma unroll 8
    for (int a = 0; a < HD; ++a) acc += hs[a] * w[a * PDIM + col];
    if (center) {
        float mean = wsum(acc) * (1.0f / PDIM);
        acc -= mean;
    }
    float* p = (t < 64) ? pA : pB;
    p[row * PDIM + col] = acc;
}

// layer-0 mask ONLY: computes pair-init values in-flight (pi+pj+rel), never
// stores pair (saves 75MB write; layer-0 pair_upd recomputes init as residual).
__global__ void __launch_bounds__(64) k_mask0(
    const float* __restrict__ pi, const float* __restrict__ pj,
    const float* __restrict__ rel_emb, const float* __restrict__ gpb,
    const float* __restrict__ cbv, float* __restrict__ mask_out) {
    __shared__ __align__(16) float pt[32][65];
    int blk = blockIdx.x;            // row*12 + seg
    int row = blk / 12, seg = blk % 12;
    int b = row / LSEQ, i = row % LSEQ;
    int t = threadIdx.x;             // 0..63
    int pl = t & 31, hq = t >> 5;
    int j0 = seg * 32;
    float piv = pi[row * 64 + t];
    const float* pjb = pj + ((size_t)b * LSEQ + j0) * 64;
#pragma unroll 8
    for (int j = 0; j < 32; ++j) {
        int r = j0 + j - i; r = r < -32 ? -32 : (r > 32 ? 32 : r); r += 32;
        pt[j][t] = piv + pjb[j * 64 + t] + rel_emb[r * 64 + t];
    }
    __syncthreads();
    // mask: dot = rsqrt(var) * sum(d * g*pbs) + sum(b*pbs)
    float vv[32];
    float sv = 0.0f;
#pragma unroll
    for (int c = 0; c < 32; ++c) { vv[c] = pt[pl][hq * 32 + c]; sv += vv[c]; }
    sv += __shfl_xor(sv, 32);
    float mean = sv * (1.0f / PDIM);
    float sd2 = 0.0f, sdg = 0.0f;
#pragma unroll
    for (int c = 0; c < 32; ++c) {
        float d = vv[c] - mean;
        sd2 = fmaf(d, d, sd2);
        sdg = fmaf(d, gpb[hq * 32 + c], sdg);
    }
    sd2 += __shfl_xor(sd2, 32);
    sdg += __shfl_xor(sdg, 32);
    float rsv = rsqrtf(sd2 * (1.0f / PDIM) + 1e-5f);
    float dot = rsv * sdg + cbv[0];
    if (hq == 0)
        atomicAdd(mask_out + i * LSEQ + j0 + pl, dot * (1.0f / (BATCH * NHEAD)));
}

// prep: fold LN g/b into W1 (b1p = b1 + bb@W1), split all pair-MLP weights into
// bf16 hi/lo, stored TRANSPOSED [out][k] for direct 16B MFMA A-frag loads.
__global__ void k_prep(const float* __restrict__ pu_ln_g, const float* __restrict__ pu_ln_b,
                       const float* __restrict__ pu_w1, const float* __restrict__ pu_b1,
                       const float* __restrict__ pu_w2,
                       const float* __restrict__ dh_ln_g, const float* __restrict__ dh_ln_b,
                       const float* __restrict__ dh_w1, const float* __restrict__ dh_b1,
                       const float* __restrict__ dh_w2,
                       unsigned short* __restrict__ w1hT, unsigned short* __restrict__ w1lT,
                       unsigned short* __restrict__ w2hT, unsigned short* __restrict__ w2lT,
                       float* __restrict__ b1p, float* __restrict__ w2c) {
    int i = blockIdx.x;              // 0..4
    int c = threadIdx.x;             // 0..63 = output row of transposed arrays
    const float *g, *bb, *w1, *b1, *w2;
    int w2s;
    if (i < 4) { g = pu_ln_g + i * 64; bb = pu_ln_b + i * 64; w1 = pu_w1 + i * 4096;
                 b1 = pu_b1 + i * 64; w2 = pu_w2 + i * 4096; w2s = 64; }
    else       { g = dh_ln_g; bb = dh_ln_b; w1 = dh_w1; b1 = dh_b1; w2 = dh_w2; w2s = 65; }
    float accb = b1[c];
    for (int k = 0; k < 64; ++k) {
        float wv = w1[k * 64 + c];
        accb += bb[k] * wv;
        unsigned short h, l;
        split_bf(g[k] * wv, h, l);                 // W1'[k][c] stored at [c][k]
        w1hT[i * 4096 + c * 64 + k] = h;
        w1lT[i * 4096 + c * 64 + k] = l;
        split_bf(w2[k * w2s + c], h, l);           // W2[k][c] stored at [c][k]
        w2hT[i * 4096 + c * 64 + k] = h;
        w2lT[i * 4096 + c * 64 + k] = l;
    }
    b1p[i * 64 + c] = accb;
    if (i == 4) w2c[c] = dh_w2[c * 65 + 64];
}

// prep for fused mask: gp[li][c] = ln_pair_g[li][c] * pbs[c],
// cb[li] = sum_c ln_pair_b[li][c]*pbs[c], pbs[c] = sum_h pb_w[li][c][h]. li=0..3.
__global__ void k_maskprep(const float* __restrict__ g, const float* __restrict__ bb,
                           const float* __restrict__ pbw, float* __restrict__ gp,
                           float* __restrict__ cb) {
    int li = blockIdx.x;             // layer 0..3
    int c = threadIdx.x;             // 0..63 (one wave)
    const float* pw = pbw + li * PDIM * NHEAD;
    float pbs = pw[c * 4] + pw[c * 4 + 1] + pw[c * 4 + 2] + pw[c * 4 + 3];
    gp[li * 64 + c] = g[li * 64 + c] * pbs;
    float s = wsum(bb[li * 64 + c] * pbs);
    if (c == 0) cb[li] = s;
}

// prep: split+transpose seq weights to bf16 hi/lo [n][k] via 64x64 LDS tiles.
// src: [K][N] row-major, per-layer stride sstride; dst: [N][K], stride dstride.
__global__ void k_split_T(const float* __restrict__ src, unsigned short* __restrict__ dh,
                          unsigned short* __restrict__ dl, int K, int N,
                          int tiles_k, int tiles_n, size_t sstride, size_t dstride) {
    __shared__ float lds[64][65];
    int bid = blockIdx.x;
    int tpl = tiles_k * tiles_n;
    int layer = bid / tpl;
    int rest = bid % tpl;
    int kt = rest / tiles_n, nt = rest % tiles_n;
    const float* s = src + layer * sstride;
    int t = threadIdx.x, c = t & 63, r0 = t >> 6;
    for (int r = r0; r < 64; r += 4)
        lds[r][c] = s[(size_t)(kt * 64 + r) * N + nt * 64 + c];
    __syncthreads();
    unsigned short* oh = dh + layer * dstride;
    unsigned short* ol = dl + layer * dstride;
    for (int r = r0; r < 64; r += 4) {
        float v = lds[c][r];                       // src[kt*64+c][nt*64+r]
        unsigned short h, l;
        split_bf(v, h, l);
        size_t o = (size_t)(nt * 64 + r) * K + kt * 64 + c;
        oh[o] = h;
        ol[o] = l;
    }
}

// ============ generic MFMA seq GEMM ============
// OUT[m][n] = epi( X[m][:]@W + bias[n] + (R?R[m][n]:0) ), M=768 rows.
// W pre-split bf16 hi/lo transposed [n][k]. ONE 32x32 wave-tile per 64-thread
// block; grid = #tiles (spreads small GEMMs across all CUs).
template<bool GELU>
__global__ void __launch_bounds__(64) k_gemm(
    const float* __restrict__ X, const unsigned short* __restrict__ wTh,
    const unsigned short* __restrict__ wTl, const float* __restrict__ bias,
    const float* __restrict__ R, float* __restrict__ OUT, int K, int N) {
    int idx = blockIdx.x;
    int lane = threadIdx.x & 63;
    int pl = lane & 31, hq = lane >> 5;
    int ntiles = N >> 5;
    int mt = idx / ntiles, nt = idx % ntiles;
    const float* xr = X + (size_t)(mt * 32 + pl) * K + 8 * hq;
    const unsigned short* bh = wTh + (size_t)(nt * 32 + pl) * K + 8 * hq;
    const unsigned short* bl = wTl + (size_t)(nt * 32 + pl) * K + 8 * hq;
    int n = nt * 32 + pl;
    float bv = bias[n];
    f32x16 acc;
#pragma unroll
    for (int r = 0; r < 16; ++r) {
        int mr = mt * 32 + (r & 3) + 8 * (r >> 2) + 4 * hq;
        acc[r] = bv + (R ? R[(size_t)mr * N + n] : 0.0f);
    }
#pragma unroll 4
    for (int s = 0; s < K; s += 16) {
        const f32x4* x4 = (const f32x4*)(xr + s);
        f32x4 xa = x4[0], xb = x4[1];
        float xv[8];
#pragma unroll
        for (int j = 0; j < 4; ++j) { xv[j] = xa[j]; xv[4 + j] = xb[j]; }
        u32x4 ah, al;
        pack8(xv, ah, al);
        bf16x8 bhv = *(const bf16x8*)(bh + s);
        bf16x8 blv = *(const bf16x8*)(bl + s);
        acc = MFMA32(as_bf(ah), bhv, acc);
        acc = MFMA32(as_bf(al), bhv, acc);
        acc = MFMA32(as_bf(ah), blv, acc);
    }
#pragma unroll
    for (int r = 0; r < 16; ++r) {
        int mr = mt * 32 + (r & 3) + 8 * (r >> 2) + 4 * hq;
        float v = acc[r];
        OUT[(size_t)mr * N + n] = GELU ? gelu_fast(v) : v;
    }
}

// seq layernorm: one row per block
__global__ void k_ln_seq(const float* __restrict__ h, const float* __restrict__ g,
                         const float* __restrict__ b, float* __restrict__ out) {
    __shared__ float red[8];
    int row = blockIdx.x;
    int t = threadIdx.x;
    int w = t >> 6, lane = t & 63;
    float v = h[row * HD + t];
    float s = wsum(v);
    if (lane == 0) red[w] = s;
    __syncthreads();
    float mean = (red[0] + red[1] + red[2] + red[3]) * (1.0f / HD);
    float d = v - mean;
    float q = wsum(d * d);
    if (lane == 0) red[4 + w] = q;
    __syncthreads();
    float var = (red[4] + red[5] + red[6] + red[7]) * (1.0f / HD);
    out[row * HD + t] = d * rsqrtf(var + 1e-5f) * g[t] + b[t];
}

// attention for one (b, nh, l) per block
__global__ void k_attn(const float* __restrict__ qkv, const float* __restrict__ mask,
                       float* __restrict__ o) {
    __shared__ __align__(16) float qs[64];
    __shared__ float sc[LSEQ];
    __shared__ float red[8];
    __shared__ float op[4][64];
    int bid = blockIdx.x;
    int l = bid % LSEQ;
    int nh = (bid / LSEQ) & 3;
    int b = bid / (LSEQ * NHEAD);
    int t = threadIdx.x;
    int w = t >> 6, lane = t & 63;
    const float* qbase = qkv + ((size_t)(b * LSEQ + l)) * 768 + nh * 64;
    if (t < 64) qs[t] = qbase[t];
    __syncthreads();
    float lmax = -1e30f;
    float myv[2];
#pragma unroll
    for (int it = 0; it < 2; ++it) {
        int m = t + it * 256;
        if (m < LSEQ) {
            const float* kb = qkv + ((size_t)(b * LSEQ + m)) * 768 + 256 + nh * 64;
            const float4* k4 = (const float4*)kb;
            const float4* q4 = (const float4*)qs;
            float acc = 0.0f;
#pragma unroll
            for (int a = 0; a < 16; ++a) {
                float4 kv = k4[a], qv = q4[a];
                acc += qv.x * kv.x + qv.y * kv.y + qv.z * kv.z + qv.w * kv.w;
            }
            float s = acc * 0.125f + mask[l * LSEQ + m];
            myv[it] = s;
            lmax = fmaxf(lmax, s);
        } else myv[it] = -1e30f;
    }
    float wm = wmax(lmax);
    if (lane == 0) red[w] = wm;
    __syncthreads();
    float gmax = fmaxf(fmaxf(red[0], red[1]), fmaxf(red[2], red[3]));
    float lsum = 0.0f;
#pragma unroll
    for (int it = 0; it < 2; ++it) {
        int m = t + it * 256;
        if (m < LSEQ) {
            float e = expf(myv[it] - gmax);
            sc[m] = e;
            lsum += e;
        }
    }
    float ws = wsum(lsum);
    if (lane == 0) red[4 + w] = ws;
    __syncthreads();
    float inv = 1.0f / (red[4] + red[5] + red[6] + red[7]);
    int d = t & 63, gq = t >> 6;
    float part = 0.0f;
    for (int m = gq * 96; m < (gq + 1) * 96; ++m)
        part += sc[m] * qkv[((size_t)(b * LSEQ + m)) * 768 + 512 + nh * 64 + d];
    op[gq][d] = part;
    __syncthreads();
    if (t < 64) {
        float ov = (op[0][t] + op[1][t] + op[2][t] + op[3][t]) * inv;
        o[((size_t)(b * LSEQ + l)) * HD + nh * 64 + t] = ov;
    }
}

// ============ MFMA pair-update: 2-phase LDS weights, early residual ============
// Block = 256 threads = 4 waves, 128 j. MODE 0: layer-0 (residual = pair-init
// computed on the fly, pair never pre-initialized in HBM) + fused next mask.
// MODE 1: mid layer (residual read) + fused next mask. MODE 2: last layer,
// fused distogram head (register reorder, dw re-stage, smem output tile).
// Plain launch bounds: libm-erff codegen allocates exactly 128 VGPR, 0 spill.
template<int MODE>
__global__ void __launch_bounds__(256) k_pair_upd(
    const float* __restrict__ ojc,   // centered oj         (B,L,64)
    const float* __restrict__ oic,   // centered oi+outer_b (B,L,64)
    const unsigned short* __restrict__ w1hT, const unsigned short* __restrict__ w1lT,
    const float* __restrict__ b1p,
    const unsigned short* __restrict__ w2hT, const unsigned short* __restrict__ w2lT,
    const float* __restrict__ b2, float* __restrict__ pair,
    const float* __restrict__ gpb, const float* __restrict__ cbv,
    float* __restrict__ mask_out,
    const float* __restrict__ ipi, const float* __restrict__ ipj,
    const float* __restrict__ rel,
    const unsigned short* __restrict__ dw1h, const unsigned short* __restrict__ dw1l,
    const float* __restrict__ db1p,
    const unsigned short* __restrict__ dw2h, const unsigned short* __restrict__ dw2l,
    const float* __restrict__ w2c, const float* __restrict__ db2,
    float* __restrict__ outg) {
    constexpr bool DIST = (MODE == 2);
    __shared__ __align__(16) char smem[DIST ? 33344 : 17472];
    short (*lw)[64][68] = (short (*)[64][68])smem;   // [2][64][68] hi|lo, padded
    int blk = blockIdx.x;            // row*3 + seg
    int row = blk / 3, seg = blk % 3;
    int b = row / LSEQ;
    int t = threadIdx.x;
    int wave = t >> 6, lane = t & 63;
    int pl = lane & 31, hq = lane >> 5;
    int jj = wave * 32 + pl;         // 0..127 within segment
    int p = seg * 128 + jj;
    const float* ojr = ojc + ((size_t)b * LSEQ + p) * 64;
    const float* oir = oic + (size_t)row * 64;
    float* prp = pair + ((size_t)row * LSEQ + p) * 64;

    // ---- EARLY residual: issue at kernel entry, consumed after MFMA1 ----
    f32x4 r0[4], r1[4];
    if constexpr (MODE == 0) {
        int l = row % LSEQ;
        int rr_ = p - l; rr_ = rr_ < -32 ? -32 : (rr_ > 32 ? 32 : rr_); rr_ += 32;
        const f32x4* i4 = (const f32x4*)(ipi + (size_t)row * 64);
        const f32x4* j4 = (const f32x4*)(ipj + ((size_t)b * LSEQ + p) * 64);
        const f32x4* e4 = (const f32x4*)(rel + rr_ * 64);
#pragma unroll
        for (int g = 0; g < 4; ++g) {
            r0[g] = i4[2 * g + hq] + j4[2 * g + hq] + e4[2 * g + hq];
            r1[g] = i4[8 + 2 * g + hq] + j4[8 + 2 * g + hq] + e4[8 + 2 * g + hq];
        }
    } else {
        const f32x4* pr4 = (const f32x4*)prp;
#pragma unroll
        for (int g = 0; g < 4; ++g) {
            r0[g] = pr4[2 * g + hq];
            r1[g] = pr4[8 + 2 * g + hq];
        }
    }

    // ---- v = oj + oi, vectorized ----
    float v[32];
    {
        const f32x4* a4 = (const f32x4*)ojr;
        const f32x4* c4 = (const f32x4*)oir;
#pragma unroll
        for (int s = 0; s < 4; ++s) {
            f32x4 a = a4[4 * s + 2 * hq], aa = a4[4 * s + 2 * hq + 1];
            f32x4 c = c4[4 * s + 2 * hq], cc = c4[4 * s + 2 * hq + 1];
#pragma unroll
            for (int j = 0; j < 4; ++j) {
                v[8 * s + j] = a[j] + c[j];
                v[8 * s + 4 + j] = aa[j] + cc[j];
            }
        }
    }
    stage_w(lw, t, w1hT, w1lT);

    // LN (mean removed upstream) + bf16 hi/lo pack via cvt_pk
    float ss = 0.0f;
#pragma unroll
    for (int i = 0; i < 32; ++i) ss = fmaf(v[i], v[i], ss);
    ss += __shfl_xor(ss, 32);
    float rs = rsqrtf(ss * (1.0f / PDIM) + 1e-5f);
#pragma unroll
    for (int i = 0; i < 32; ++i) v[i] *= rs;
    u32x4 zh[4], zl[4];
#pragma unroll
    for (int s = 0; s < 4; ++s) pack8(v + 8 * s, zh[s], zl[s]);

    const f32x4* b14 = (const f32x4*)b1p;
    f32x4 bi0[4], bi1[4];
#pragma unroll
    for (int g = 0; g < 4; ++g) { bi0[g] = b14[2 * g + hq]; bi1[g] = b14[8 + 2 * g + hq]; }

    __syncthreads();   // w1 staged

    f32x16 acc0, acc1;
#pragma unroll
    for (int r = 0; r < 16; ++r) {
        acc0[r] = bi0[r >> 2][r & 3];
        acc1[r] = bi1[r >> 2][r & 3];
    }
#pragma unroll
    for (int s = 0; s < 4; ++s) {
        int ko = 16 * s + 8 * hq;
        bf16x8 a0h = ld8(&lw[0][pl][ko]);
        bf16x8 a0l = ld8(&lw[1][pl][ko]);
        bf16x8 a1h = ld8(&lw[0][32 + pl][ko]);
        bf16x8 a1l = ld8(&lw[1][32 + pl][ko]);
        bf16x8 zhs = as_bf(zh[s]), zls = as_bf(zl[s]);
        acc0 = MFMA32(a0h, zhs, acc0);
        acc0 = MFMA32(a0h, zls, acc0);
        acc0 = MFMA32(a0l, zhs, acc0);
        acc1 = MFMA32(a1h, zhs, acc1);
        acc1 = MFMA32(a1h, zls, acc1);
        acc1 = MFMA32(a1l, zhs, acc1);
    }
    __syncthreads();   // all waves done reading w1
    stage_w(lw, t, w2hT, w2lT);  // load latency hides under gelu below

    float u0[16], u1[16];
#pragma unroll
    for (int r = 0; r < 16; ++r) { u0[r] = gelu_erf(acc0[r]); u1[r] = gelu_erf(acc1[r]); }

    // bias2 broadcast loads (L2-hot)
    f32x4 q0[4], q1[4];
    {
        const f32x4* b24 = (const f32x4*)b2;
#pragma unroll
        for (int g = 0; g < 4; ++g) {
            q0[g] = b24[2 * g + hq];
            q1[g] = b24[8 + 2 * g + hq];
        }
    }

    float rA0[4], rB0[4], rA1[4], rB1[4];
#pragma unroll
    for (int i = 0; i < 4; ++i) {
        rA0[i] = __shfl_xor(hq ? u0[i] : u0[4 + i], 32);
        rB0[i] = __shfl_xor(hq ? u0[8 + i] : u0[12 + i], 32);
        rA1[i] = __shfl_xor(hq ? u1[i] : u1[4 + i], 32);
        rB1[i] = __shfl_xor(hq ? u1[8 + i] : u1[12 + i], 32);
    }
    u32x4 uh[4], ul[4];
#pragma unroll
    for (int s = 0; s < 4; ++s) {
        int tt = s >> 1, q = s & 1;
        float fg[8];
#pragma unroll
        for (int i = 0; i < 4; ++i) {
            float own_f = q ? (tt ? u1[8 + i] : u0[8 + i]) : (tt ? u1[i] : u0[i]);
            float own_s = q ? (tt ? u1[12 + i] : u0[12 + i]) : (tt ? u1[4 + i] : u0[4 + i]);
            float rcv   = q ? (tt ? rB1[i] : rB0[i]) : (tt ? rA1[i] : rA0[i]);
            fg[i]     = hq ? rcv : own_f;
            fg[4 + i] = hq ? own_s : rcv;
        }
        pack8(fg, uh[s], ul[s]);
    }

    __syncthreads();   // w2 staged

    f32x16 c0, c1;
#pragma unroll
    for (int r = 0; r < 16; ++r) {
        int g = r >> 2, i = r & 3;
        c0[r] = q0[g][i] + r0[g][i];
        c1[r] = q1[g][i] + r1[g][i];
    }
#pragma unroll
    for (int s = 0; s < 4; ++s) {
        int ko = 16 * s + 8 * hq;
        bf16x8 a0h = ld8(&lw[0][pl][ko]);
        bf16x8 a0l = ld8(&lw[1][pl][ko]);
        bf16x8 a1h = ld8(&lw[0][32 + pl][ko]);
        bf16x8 a1l = ld8(&lw[1][32 + pl][ko]);
        bf16x8 uhs = as_bf(uh[s]), uls = as_bf(ul[s]);
        c0 = MFMA32(a0h, uhs, c0);
        c0 = MFMA32(a0h, uls, c0);
        c0 = MFMA32(a0l, uhs, c0);
        c1 = MFMA32(a1h, uhs, c1);
        c1 = MFMA32(a1h, uls, c1);
        c1 = MFMA32(a1l, uhs, c1);
    }

    if constexpr (!DIST) {
        // fused mask for next layer: LN(final pair) . pbsum, mean over b via atomics
        const f32x4* gp4 = (const f32x4*)gpb;
        f32x4 gp0[4], gp1[4];
#pragma unroll
        for (int g = 0; g < 4; ++g) { gp0[g] = gp4[2 * g + hq]; gp1[g] = gp4[8 + 2 * g + hq]; }
        float sv = 0.0f;
#pragma unroll
        for (int r = 0; r < 16; ++r) sv += c0[r] + c1[r];
        sv += __shfl_xor(sv, 32);
        float mean = sv * (1.0f / PDIM);
        float sd2 = 0.0f, sdg = 0.0f;
#pragma unroll 4
        for (int r = 0; r < 16; ++r) {
            int g = r >> 2, i = r & 3;
            float d0 = c0[r] - mean, d1 = c1[r] - mean;
            sd2 = fmaf(d0, d0, sd2);
            sd2 = fmaf(d1, d1, sd2);
            sdg = fmaf(d0, gp0[g][i], sdg);
            sdg = fmaf(d1, gp1[g][i], sdg);
        }
        sd2 += __shfl_xor(sd2, 32);
        sdg += __shfl_xor(sdg, 32);
        float rsv = rsqrtf(sd2 * (1.0f / PDIM) + 1e-5f);
        float dot = rsv * sdg + cbv[0];
        if (hq == 0)
            atomicAdd(mask_out + (row % LSEQ) * LSEQ + p, dot * (1.0f / (BATCH * NHEAD)));
        // store updated pair: lane-private float4 x8
        f32x4* pw4 = (f32x4*)prp;
#pragma unroll
        for (int g = 0; g < 4; ++g) {
            f32x4 s0, s1;
#pragma unroll
            for (int i = 0; i < 4; ++i) { s0[i] = c0[4 * g + i]; s1[i] = c1[4 * g + i]; }
            pw4[2 * g + hq] = s0;
            pw4[8 + 2 * g + hq] = s1;
        }
    } else {
        // ---- fused distogram head; fragment->k-order reorder in registers ----
        // partner lane (xor 32) holds exactly the interleaved 4-channel groups:
        float ra[4], rb[4], rc[4], rd[4];
#pragma unroll
        for (int i = 0; i < 4; ++i) {
            ra[i] = __shfl_xor(hq ? c0[i] : c0[4 + i], 32);
            rb[i] = __shfl_xor(hq ? c0[8 + i] : c0[12 + i], 32);
            rc[i] = __shfl_xor(hq ? c1[i] : c1[4 + i], 32);
            rd[i] = __shfl_xor(hq ? c1[8 + i] : c1[12 + i], 32);
        }
        float v2[32];
#pragma unroll
        for (int i = 0; i < 4; ++i) {
            v2[i]      = hq ? ra[i] : c0[i];
            v2[4 + i]  = hq ? c0[4 + i] : ra[i];
            v2[8 + i]  = hq ? rb[i] : c0[8 + i];
            v2[12 + i] = hq ? c0[12 + i] : rb[i];
            v2[16 + i] = hq ? rc[i] : c1[i];
            v2[20 + i] = hq ? c1[4 + i] : rc[i];
            v2[24 + i] = hq ? rd[i] : c1[8 + i];
            v2[28 + i] = hq ? c1[12 + i] : rd[i];
        }
        __syncthreads();   // all waves done reading pu w2
        stage_w(lw, t, dw1h, dw1l);

        float sm = 0.0f;
#pragma unroll
        for (int i = 0; i < 32; ++i) sm += v2[i];
        sm += __shfl_xor(sm, 32);
        float mean = sm * (1.0f / PDIM);
        float ss2 = 0.0f;
#pragma unroll
        for (int i = 0; i < 32; ++i) { v2[i] -= mean; ss2 = fmaf(v2[i], v2[i], ss2); }
        ss2 += __shfl_xor(ss2, 32);
        float rs2 = rsqrtf(ss2 * (1.0f / PDIM) + 1e-5f);
#pragma unroll
        for (int i = 0; i < 32; ++i) v2[i] *= rs2;
#pragma unroll
        for (int s = 0; s < 4; ++s) pack8(v2 + 8 * s, zh[s], zl[s]);

        const f32x4* d14 = (const f32x4*)db1p;
        const f32x4* d24 = (const f32x4*)db2;
        const f32x4* wc4 = (const f32x4*)w2c;
        f32x4 di0[4], di1[4], e0[4], e1[4], wc0[4], wc1[4];
#pragma unroll
        for (int g = 0; g < 4; ++g) {
            di0[g] = d14[2 * g + hq]; di1[g] = d14[8 + 2 * g + hq];
            e0[g] = d24[2 * g + hq];  e1[g] = d24[8 + 2 * g + hq];
            wc0[g] = wc4[2 * g + hq]; wc1[g] = wc4[8 + 2 * g + hq];
        }
        __syncthreads();   // dw1 staged

#pragma unroll
        for (int r = 0; r < 16; ++r) {
            acc0[r] = di0[r >> 2][r & 3];
            acc1[r] = di1[r >> 2][r & 3];
        }
#pragma unroll
        for (int s = 0; s < 4; ++s) {
            int ko = 16 * s + 8 * hq;
            bf16x8 a0h = ld8(&lw[0][pl][ko]);
            bf16x8 a0l = ld8(&lw[1][pl][ko]);
            bf16x8 a1h = ld8(&lw[0][32 + pl][ko]);
            bf16x8 a1l = ld8(&lw[1][32 + pl][ko]);
            bf16x8 zhs = as_bf(zh[s]), zls = as_bf(zl[s]);
            acc0 = MFMA32(a0h, zhs, acc0);
            acc0 = MFMA32(a0h, zls, acc0);
            acc0 = MFMA32(a0l, zhs, acc0);
            acc1 = MFMA32(a1h, zhs, acc1);
            acc1 = MFMA32(a1h, zls, acc1);
            acc1 = MFMA32(a1l, zhs, acc1);
        }
        __syncthreads();   // done reading dw1
        stage_w(lw, t, dw2h, dw2l);

        float p64 = 0.0f;
#pragma unroll
        for (int r = 0; r < 16; ++r) {
            int g = r >> 2, i = r & 3;
            u0[r] = gelu_erf(acc0[r]);
            u1[r] = gelu_erf(acc1[r]);
            p64 = fmaf(u0[r], wc0[g][i], p64);
            p64 = fmaf(u1[r], wc1[g][i], p64);
        }
        p64 += __shfl_xor(p64, 32);
#pragma unroll
        for (int i = 0; i < 4; ++i) {
            rA0[i] = __shfl_xor(hq ? u0[i] : u0[4 + i], 32);
            rB0[i] = __shfl_xor(hq ? u0[8 + i] : u0[12 + i], 32);
            rA1[i] = __shfl_xor(hq ? u1[i] : u1[4 + i], 32);
            rB1[i] = __shfl_xor(hq ? u1[8 + i] : u1[12 + i], 32);
        }
#pragma unroll
        for (int s = 0; s < 4; ++s) {
            int tt = s >> 1, q = s & 1;
            float fg[8];
#pragma unroll
            for (int i = 0; i < 4; ++i) {
                float own_f = q ? (tt ? u1[8 + i] : u0[8 + i]) : (tt ? u1[i] : u0[i]);
                float own_s = q ? (tt ? u1[12 + i] : u0[12 + i]) : (tt ? u1[4 + i] : u0[4 + i]);
                float rcv   = q ? (tt ? rB1[i] : rB0[i]) : (tt ? rA1[i] : rA0[i]);
                fg[i]     = hq ? rcv : own_f;
                fg[4 + i] = hq ? own_s : rcv;
            }
            pack8(fg, uh[s], ul[s]);
        }
        __syncthreads();   // dw2 staged

#pragma unroll
        for (int r = 0; r < 16; ++r) {
            c0[r] = e0[r >> 2][r & 3];
            c1[r] = e1[r >> 2][r & 3];
        }
#pragma unroll
        for (int s = 0; s < 4; ++s) {
            int ko = 16 * s + 8 * hq;
            bf16x8 a0h = ld8(&lw[0][pl][ko]);
            bf16x8 a0l = ld8(&lw[1][pl][ko]);
            bf16x8 a1h = ld8(&lw[0][32 + pl][ko]);
            bf16x8 a1l = ld8(&lw[1][32 + pl][ko]);
            bf16x8 uhs = as_bf(uh[s]), uls = as_bf(ul[s]);
            c0 = MFMA32(a0h, uhs, c0);
            c0 = MFMA32(a0h, uls, c0);
            c0 = MFMA32(a0l, uhs, c0);
            c1 = MFMA32(a1h, uhs, c1);
            c1 = MFMA32(a1h, uls, c1);
            c1 = MFMA32(a1l, uhs, c1);
        }
        __syncthreads();   // lw dead everywhere -> reuse smem as output tile
        float (*pt)[65] = (float (*)[65])smem;
#pragma unroll
        for (int r = 0; r < 16; ++r) {
            int rr = (r & 3) + 8 * (r >> 2) + 4 * hq;
            pt[jj][rr] = c0[r];
            pt[jj][32 + rr] = c1[r];
        }
        if (hq == 0) pt[jj][64] = p64 + db2[64];
        __syncthreads();
        float4* dst = (float4*)(outg + ((size_t)row * LSEQ + seg * 128) * NBINS);
        const float4* srcl = (const float4*)&pt[0][0];
        for (int n = t; n < 128 * NBINS / 4; n += 256) dst[n] = srcl[n];
    }
}

// out = (out + out^T(1,2)) / 2, in place.  One 16x16 (l,m) tile pair per block
// (upper triangle incl diagonal); lanes run along the contiguous 65-bin axis.
__global__ void k_sym(float* __restrict__ out) {
    int u = blockIdx.x;
    int b = 0;
    if (u >= NTRI) { b = 1; u -= NTRI; }
    int lt = 0, rem = NTT;
    while (u >= rem) { u -= rem; ++lt; --rem; }
    int mt = lt + u;
    int t = threadIdx.x;
    int g = t >> 6, lane = t & 63;
    float* ob = out + (size_t)b * LSEQ * LSEQ * NBINS;
    for (int e = g; e < 256; e += 4) {
        int i = e >> 4, j = e & 15;
        if (lt == mt && j < i) continue;
        size_t ia = ((size_t)(lt * 16 + i) * LSEQ + (mt * 16 + j)) * NBINS;
        size_t ib = ((size_t)(mt * 16 + j) * LSEQ + (lt * 16 + i)) * NBINS;
        for (int k = lane; k < NBINS; k += 64) {
            float a = ob[ia + k], c = ob[ib + k];
            float vv = 0.5f * (a + c);
            ob[ia + k] = vv;
            if (ia != ib) ob[ib + k] = vv;
        }
    }
}

extern "C" void kernel_launch(void* const* d_in, const int* in_sizes, int n_in,
                              void* d_out, int out_size, void* d_ws, size_t ws_size,
                              hipStream_t stream) {
    const float* x        = (const float*)d_in[0];
    const float* rp_w     = (const float*)d_in[1];
    const float* rp_b     = (const float*)d_in[2];
    const float* pos      = (const float*)d_in[3];
    const float* pii_w    = (const float*)d_in[4];
    const float* pii_b    = (const float*)d_in[5];
    const float* pij_w    = (const float*)d_in[6];
    const float* pij_b    = (const float*)d_in[7];
    const float* rel_emb  = (const float*)d_in[8];
    const float* ln_seq_g = (const float*)d_in[9];
    const float* ln_seq_b = (const float*)d_in[10];
    const float* ln_pair_g= (const float*)d_in[11];
    const float* ln_pair_b= (const float*)d_in[12];
    const float* pb_w     = (const float*)d_in[13];
    const float* in_w     = (const float*)d_in[14];
    const float* in_b     = (const float*)d_in[15];
    const float* out_w    = (const float*)d_in[16];
    const float* out_b    = (const float*)d_in[17];
    const float* ff_ln_g  = (const float*)d_in[18];
    const float* ff_ln_b  = (const float*)d_in[19];
    const float* ff_w1    = (const float*)d_in[20];
    const float* ff_b1    = (const float*)d_in[21];
    const float* ff_w2    = (const float*)d_in[22];
    const float* ff_b2    = (const float*)d_in[23];
    const float* pu_ln_g  = (const float*)d_in[24];
    const float* pu_ln_b  = (const float*)d_in[25];
    const float* pu_w1    = (const float*)d_in[26];
    const float* pu_b1    = (const float*)d_in[27];
    const float* pu_w2    = (const float*)d_in[28];
    const float* pu_b2    = (const float*)d_in[29];
    const float* outer_w  = (const float*)d_in[30];
    const float* outer_b  = (const float*)d_in[31];
    const float* dh_ln_g  = (const float*)d_in[32];
    const float* dh_ln_b  = (const float*)d_in[33];
    const float* dh_w1    = (const float*)d_in[34];
    const float* dh_b1    = (const float*)d_in[35];
    const float* dh_w2    = (const float*)d_in[36];
    const float* dh_b2    = (const float*)d_in[37];
    float* outp = (float*)d_out;

    float* W = (float*)d_ws;
    float* h    = W;  W += BATCH * LSEQ * HD;
    float* sn   = W;  W += BATCH * LSEQ * HD;
    float* qkv  = W;  W += BATCH * LSEQ * 3 * HD;
    float* ob   = W;  W += BATCH * LSEQ * HD;
    float* mid  = W;  W += BATCH * LSEQ * 4 * HD;
    float* maskA= W;  W += LSEQ * LSEQ;
    float* maskB= W;  W += LSEQ * LSEQ;
    float* poi  = W;  W += BATCH * LSEQ * PDIM;
    float* poj  = W;  W += BATCH * LSEQ * PDIM;
    float* poi0 = W;  W += BATCH * LSEQ * PDIM;   // pair-init projections (kept)
    float* poj0 = W;  W += BATCH * LSEQ * PDIM;
    float* b1p  = W;  W += 5 * 64;
    float* w2c  = W;  W += 64;
    float* gpb  = W;  W += 4 * 64;
    float* cbv  = W;  W += 64;
    unsigned short* w1hT = (unsigned short*)W;  W += 5 * 2048;
    unsigned short* w1lT = (unsigned short*)W;  W += 5 * 2048;
    unsigned short* w2hT = (unsigned short*)W;  W += 5 * 2048;
    unsigned short* w2lT = (unsigned short*)W;  W += 5 * 2048;
    // seq-GEMM split/transposed weights (bf16 hi/lo), per-layer strides in elems
    unsigned short* qwT_h = (unsigned short*)W;  W += 4 * 196608 / 2;
    unsigned short* qwT_l = (unsigned short*)W;  W += 4 * 196608 / 2;
    unsigned short* owT_h = (unsigned short*)W;  W += 4 * 65536 / 2;
    unsigned short* owT_l = (unsigned short*)W;  W += 4 * 65536 / 2;
    unsigned short* f1T_h = (unsigned short*)W;  W += 4 * 262144 / 2;
    unsigned short* f1T_l = (unsigned short*)W;  W += 4 * 262144 / 2;
    unsigned short* f2T_h = (unsigned short*)W;  W += 4 * 262144 / 2;
    unsigned short* f2T_l = (unsigned short*)W;  W += 4 * 262144 / 2;
    float* pair = W;  W += (size_t)BATCH * LSEQ * LSEQ * PDIM;

    const int rows = BATCH * LSEQ;   // 768

    k_prep<<<5, 64, 0, stream>>>(pu_ln_g, pu_ln_b, pu_w1, pu_b1, pu_w2,
                                 dh_ln_g, dh_ln_b, dh_w1, dh_b1, dh_w2,
                                 w1hT, w1lT, w2hT, w2lT, b1p, w2c);
    k_maskprep<<<4, 64, 0, stream>>>(ln_pair_g, ln_pair_b, pb_w, gpb, cbv);
    k_split_T<<<4 * 4 * 12, 256, 0, stream>>>(in_w,  qwT_h, qwT_l, 256, 768,  4, 12, 196608, 196608);
    k_split_T<<<4 * 4 * 4,  256, 0, stream>>>(out_w, owT_h, owT_l, 256, 256,  4, 4,  65536,  65536);
    k_split_T<<<4 * 4 * 16, 256, 0, stream>>>(ff_w1, f1T_h, f1T_l, 256, 1024, 4, 16, 262144, 262144);
    k_split_T<<<4 * 16 * 4, 256, 0, stream>>>(ff_w2, f2T_h, f2T_l, 1024, 256, 16, 4, 262144, 262144);
    k_h_init<<<rows, 256, 0, stream>>>(x, rp_w, rp_b, pos, h);
    k_proj2<<<rows, 128, 0, stream>>>(h, pii_w, pij_w, pii_b, pij_b, 0, poi0, poj0);
    hipMemsetAsync(maskA, 0, LSEQ * LSEQ * sizeof(float), stream);
    // layer-0 mask from on-the-fly pair init (pair never written to HBM here)
    k_mask0<<<rows * 12, 64, 0, stream>>>(poi0, poj0, rel_emb, gpb, cbv, maskA);

    float* mcur = maskA;
    float* mnext = maskB;
    for (int i = 0; i < 4; ++i) {
        k_ln_seq<<<rows, 256, 0, stream>>>(h, ln_seq_g + i * HD, ln_seq_b + i * HD, sn);
        // qkv = sn @ in_w + in_b   (24 x 24 tiles, 1-wave blocks)
        k_gemm<false><<<576, 64, 0, stream>>>(sn, qwT_h + i * 196608, qwT_l + i * 196608,
                                              in_b + i * 768, nullptr, qkv, 256, 768);
        k_attn<<<BATCH * NHEAD * LSEQ, 256, 0, stream>>>(qkv, mcur, ob);
        // h += ob @ out_w + out_b  (24 x 8 tiles)
        k_gemm<false><<<192, 64, 0, stream>>>(ob, owT_h + i * 65536, owT_l + i * 65536,
                                              out_b + i * 256, h, h, 256, 256);
        k_ln_seq<<<rows, 256, 0, stream>>>(h, ff_ln_g + i * HD, ff_ln_b + i * HD, sn);
        // mid = gelu(sn @ ff_w1 + b1)  (24 x 32 tiles)
        k_gemm<true><<<768, 64, 0, stream>>>(sn, f1T_h + i * 262144, f1T_l + i * 262144,
                                             ff_b1 + i * 1024, nullptr, mid, 256, 1024);
        // h += mid @ ff_w2 + b2  (24 x 8 tiles)
        k_gemm<false><<<192, 64, 0, stream>>>(mid, f2T_h + i * 262144, f2T_l + i * 262144,
                                              ff_b2 + i * 256, h, h, 1024, 256);
        // centered oi+outer_b (poi) and centered oj (poj)
        k_proj2<<<rows, 128, 0, stream>>>(h, outer_w + i * 2 * HD * PDIM,
                                          outer_w + i * 2 * HD * PDIM + HD * PDIM,
                                          outer_b + i * PDIM, nullptr, 1, poi, poj);
        if (i == 0) {
            hipMemsetAsync(mnext, 0, LSEQ * LSEQ * sizeof(float), stream);
            // layer 0: residual = pair-init computed in-kernel (no pair read)
            k_pair_upd<0><<<rows * 3, 256, 0, stream>>>(
                poj, poi,
                w1hT, w1lT, b1p, w2hT, w2lT, pu_b2, pair,
                gpb + 64, cbv + 1, mnext, poi0, poj0, rel_emb,
                nullptr, nullptr, nullptr, nullptr, nullptr, nullptr, nullptr, nullptr);
            float* tmp = mcur; mcur = mnext; mnext = tmp;
        } else if (i < 3) {
            hipMemsetAsync(mnext, 0, LSEQ * LSEQ * sizeof(float), stream);
            k_pair_upd<1><<<rows * 3, 256, 0, stream>>>(
                poj, poi,
                w1hT + i * 4096, w1lT + i * 4096, b1p + i * 64,
                w2hT + i * 4096, w2lT + i * 4096, pu_b2 + i * PDIM, pair,
                gpb + (i + 1) * 64, cbv + (i + 1), mnext,
                nullptr, nullptr, nullptr,
                nullptr, nullptr, nullptr, nullptr, nullptr, nullptr, nullptr, nullptr);
            float* tmp = mcur; mcur = mnext; mnext = tmp;
        } else {
            // last layer: pair update fused with distogram head; pair never stored
            k_pair_upd<2><<<rows * 3, 256, 0, stream>>>(
                poj, poi,
                w1hT + 3 * 4096, w1lT + 3 * 4096, b1p + 3 * 64,
                w2hT + 3 * 4096, w2lT + 3 * 4096, pu_b2 + 3 * PDIM, pair,
                nullptr, nullptr, nullptr,
                nullptr, nullptr, nullptr,
                w1hT + 4 * 4096, w1lT + 4 * 4096, b1p + 4 * 64,
                w2hT + 4 * 4096, w2lT + 4 * 4096, w2c, dh_b2, outp);
        }
    }

    k_sym<<<2 * NTRI, 256, 0, stream>>>(outp);
}

// Round 11
// 1018.854 us; speedup vs baseline: 1.1238x; 1.0455x over previous
//
#include <hip/hip_runtime.h>
#include <math.h>

#define LSEQ 384
#define HD 256
#define PDIM 64
#define NHEAD 4
#define NBINS 65
#define BATCH 2
#define NTT (LSEQ / 16)
#define NTRI (NTT * (NTT + 1) / 2)

typedef __attribute__((ext_vector_type(8))) short bf16x8;
typedef __attribute__((ext_vector_type(16))) float f32x16;
typedef __attribute__((ext_vector_type(4))) float f32x4;
typedef __attribute__((ext_vector_type(4))) unsigned u32x4;
typedef __attribute__((ext_vector_type(4))) short s16x4;
#define MFMA32(a, b, c) __builtin_amdgcn_mfma_f32_32x32x16_bf16(a, b, c, 0, 0, 0)

// ---- DPP-based wave64 reductions (VALU pipe, not LDS) ----
template<int CTRL, int RMASK>
__device__ __forceinline__ float dpp_sum_step(float v) {
    int x = __builtin_amdgcn_update_dpp(0, __float_as_int(v), CTRL, RMASK, 0xf, true);
    return v + __int_as_float(x);
}
template<int CTRL, int RMASK>
__device__ __forceinline__ float dpp_max_step(float v) {
    int x = __builtin_amdgcn_update_dpp(__float_as_int(v), __float_as_int(v), CTRL, RMASK, 0xf, false);
    return fmaxf(v, __int_as_float(x));
}
__device__ __forceinline__ float wsum(float v) {
    v = dpp_sum_step<0x111, 0xf>(v);
    v = dpp_sum_step<0x112, 0xf>(v);
    v = dpp_sum_step<0x114, 0xf>(v);
    v = dpp_sum_step<0x118, 0xf>(v);
    v = dpp_sum_step<0x142, 0xa>(v);
    v = dpp_sum_step<0x143, 0xc>(v);
    return __int_as_float(__builtin_amdgcn_readlane(__float_as_int(v), 63));
}
__device__ __forceinline__ float wmax(float v) {
    v = dpp_max_step<0x111, 0xf>(v);
    v = dpp_max_step<0x112, 0xf>(v);
    v = dpp_max_step<0x114, 0xf>(v);
    v = dpp_max_step<0x118, 0xf>(v);
    v = dpp_max_step<0x142, 0xa>(v);
    v = dpp_max_step<0x143, 0xc>(v);
    return __int_as_float(__builtin_amdgcn_readlane(__float_as_int(v), 63));
}

// libm erf gelu — used in k_pair_upd (stable codegen, zero spill).
__device__ __forceinline__ float gelu_erf(float x) {
    return 0.5f * x * (1.0f + erff(x * 0.70710678f));
}

// fast poly gelu (A&S 7.1.26, |erf err| <= 1.5e-7) on schedulable HIP
// intrinsics — used ONLY in k_gemm's epilogue (low register pressure).
__device__ __forceinline__ float gelu_fast(float x) {
    float az = fabsf(x) * 0.70710678f;
    float t = __fdividef(1.0f, fmaf(0.3275911f, az, 1.0f));
    float p = fmaf(fmaf(fmaf(fmaf(1.061405429f, t, -1.453152027f), t,
                  1.421413741f), t, -0.284496736f), t, 0.254829592f) * t;
    float e = __expf(-az * az);
    float er = fmaf(-p, e, 1.0f);
    float s = x < 0.0f ? -er : er;
    return 0.5f * x * (1.0f + s);
}

// bf16 RNE conversion + error-compensated split: x ~= hi + lo
__device__ __forceinline__ unsigned short f2bf(float x) {
    unsigned u = __float_as_uint(x);
    unsigned r = (u + 0x7fff + ((u >> 16) & 1)) >> 16;
    return (unsigned short)r;
}
__device__ __forceinline__ float bf2f(unsigned short h) {
    return __uint_as_float(((unsigned)h) << 16);
}
__device__ __forceinline__ void split_bf(float x, unsigned short& h, unsigned short& l) {
    h = f2bf(x);
    l = f2bf(x - bf2f(h));
}

// HW packed f32->bf16 RNE (identical rounding to f2bf), 2 values per inst.
__device__ __forceinline__ unsigned cvt_pk_bf(float lo, float hi) {
    unsigned r;
    asm("v_cvt_pk_bf16_f32 %0, %1, %2" : "=v"(r) : "v"(lo), "v"(hi));
    return r;
}
// pack 8 floats -> hi bf16x8 + lo bf16x8 (error-compensated split), as u32x4
__device__ __forceinline__ void pack8(const float* v, u32x4& h, u32x4& l) {
#pragma unroll
    for (int j = 0; j < 4; ++j) {
        float a = v[2 * j], b = v[2 * j + 1];
        unsigned hp = cvt_pk_bf(a, b);
        float ra = a - __uint_as_float(hp << 16);
        float rb = b - __uint_as_float(hp & 0xffff0000u);
        h[j] = hp;
        l[j] = cvt_pk_bf(ra, rb);
    }
}
__device__ __forceinline__ bf16x8 as_bf(u32x4 x) {
    union { u32x4 u; bf16x8 b; } c; c.u = x; return c.b;
}
// load a bf16x8 fragment from LDS (8-byte aligned, padded-stride rows)
__device__ __forceinline__ bf16x8 ld8(const short* p) {
    s16x4 a = *(const s16x4*)p;
    s16x4 b = *(const s16x4*)(p + 4);
    bf16x8 r;
    r[0] = a[0]; r[1] = a[1]; r[2] = a[2]; r[3] = a[3];
    r[4] = b[0]; r[5] = b[1]; r[6] = b[2]; r[7] = b[3];
    return r;
}

// cooperative stage of one MLP's hi/lo weight pair into padded LDS
__device__ __forceinline__ void stage_w(short (*lw)[64][68], int t,
                                        const unsigned short* __restrict__ srcA,
                                        const unsigned short* __restrict__ srcB) {
    for (int idx = t; idx < 2048; idx += 256) {
        int rr2 = idx >> 5, cc2 = (idx & 31) * 2;
        *(unsigned*)&lw[0][rr2][cc2] = *(const unsigned*)(srcA + rr2 * 64 + cc2);
        *(unsigned*)&lw[1][rr2][cc2] = *(const unsigned*)(srcB + rr2 * 64 + cc2);
    }
}

// h[b,l,:] = x[b,l,:] @ rp_w + rp_b + pos[l,:]
__global__ void k_h_init(const float* __restrict__ x, const float* __restrict__ rp_w,
                         const float* __restrict__ rp_b, const float* __restrict__ pos,
                         float* __restrict__ h) {
    __shared__ float xs[48];
    int row = blockIdx.x;            // b*L + l
    int l = row % LSEQ;
    int t = threadIdx.x;
    if (t < 48) xs[t] = x[row * 48 + t];
    __syncthreads();
    float acc = rp_b[t] + pos[l * HD + t];
#pragma unroll 8
    for (int a = 0; a < 48; ++a) acc += xs[a] * rp_w[a * HD + t];
    h[row * HD + t] = acc;
}

// pA[row,:] = h[row,:] @ wA (+ bA);  pB[row,:] = h[row,:] @ wB (+ bB)
// center!=0: subtract per-row mean (LN-mean elimination downstream)
__global__ void k_proj2(const float* __restrict__ h, const float* __restrict__ wA,
                        const float* __restrict__ wB, const float* __restrict__ bA,
                        const float* __restrict__ bB, int center,
                        float* __restrict__ pA, float* __restrict__ pB) {
    __shared__ float hs[HD];
    int row = blockIdx.x;
    int t = threadIdx.x;
    hs[t] = h[row * HD + t];
    hs[t + 128] = h[row * HD + t + 128];
    __syncthreads();
    int col = t & 63;
    const float* w = (t < 64) ? wA : wB;
    const float* bias = (t < 64) ? bA : bB;
    float acc = bias ? bias[col] : 0.0f;
#pragma unroll 8
    for (int a = 0; a < HD; ++a) acc += hs[a] * w[a * PDIM + col];
    if (center) {
        float mean = wsum(acc) * (1.0f / PDIM);
        acc -= mean;
    }
    float* p = (t < 64) ? pA : pB;
    p[row * PDIM + col] = acc;
}

// layer-0 mask ONLY: computes pair-init values in-flight (pi+pj+rel), never
// stores pair (saves 75MB write; layer-0 pair_upd recomputes init as residual).
__global__ void __launch_bounds__(64) k_mask0(
    const float* __restrict__ pi, const float* __restrict__ pj,
    const float* __restrict__ rel_emb, const float* __restrict__ gpb,
    const float* __restrict__ cbv, float* __restrict__ mask_out) {
    __shared__ __align__(16) float pt[32][65];
    int blk = blockIdx.x;            // row*12 + seg
    int row = blk / 12, seg = blk % 12;
    int b = row / LSEQ, i = row % LSEQ;
    int t = threadIdx.x;             // 0..63
    int pl = t & 31, hq = t >> 5;
    int j0 = seg * 32;
    float piv = pi[row * 64 + t];
    const float* pjb = pj + ((size_t)b * LSEQ + j0) * 64;
#pragma unroll 8
    for (int j = 0; j < 32; ++j) {
        int r = j0 + j - i; r = r < -32 ? -32 : (r > 32 ? 32 : r); r += 32;
        pt[j][t] = piv + pjb[j * 64 + t] + rel_emb[r * 64 + t];
    }
    __syncthreads();
    // mask: dot = rsqrt(var) * sum(d * g*pbs) + sum(b*pbs)
    float vv[32];
    float sv = 0.0f;
#pragma unroll
    for (int c = 0; c < 32; ++c) { vv[c] = pt[pl][hq * 32 + c]; sv += vv[c]; }
    sv += __shfl_xor(sv, 32);
    float mean = sv * (1.0f / PDIM);
    float sd2 = 0.0f, sdg = 0.0f;
#pragma unroll
    for (int c = 0; c < 32; ++c) {
        float d = vv[c] - mean;
        sd2 = fmaf(d, d, sd2);
        sdg = fmaf(d, gpb[hq * 32 + c], sdg);
    }
    sd2 += __shfl_xor(sd2, 32);
    sdg += __shfl_xor(sdg, 32);
    float rsv = rsqrtf(sd2 * (1.0f / PDIM) + 1e-5f);
    float dot = rsv * sdg + cbv[0];
    if (hq == 0)
        atomicAdd(mask_out + i * LSEQ + j0 + pl, dot * (1.0f / (BATCH * NHEAD)));
}

// prep: fold LN g/b into W1 (b1p = b1 + bb@W1), split all pair-MLP weights into
// bf16 hi/lo, stored TRANSPOSED [out][k] for direct 16B MFMA A-frag loads.
__global__ void k_prep(const float* __restrict__ pu_ln_g, const float* __restrict__ pu_ln_b,
                       const float* __restrict__ pu_w1, const float* __restrict__ pu_b1,
                       const float* __restrict__ pu_w2,
                       const float* __restrict__ dh_ln_g, const float* __restrict__ dh_ln_b,
                       const float* __restrict__ dh_w1, const float* __restrict__ dh_b1,
                       const float* __restrict__ dh_w2,
                       unsigned short* __restrict__ w1hT, unsigned short* __restrict__ w1lT,
                       unsigned short* __restrict__ w2hT, unsigned short* __restrict__ w2lT,
                       float* __restrict__ b1p, float* __restrict__ w2c) {
    int i = blockIdx.x;              // 0..4
    int c = threadIdx.x;             // 0..63 = output row of transposed arrays
    const float *g, *bb, *w1, *b1, *w2;
    int w2s;
    if (i < 4) { g = pu_ln_g + i * 64; bb = pu_ln_b + i * 64; w1 = pu_w1 + i * 4096;
                 b1 = pu_b1 + i * 64; w2 = pu_w2 + i * 4096; w2s = 64; }
    else       { g = dh_ln_g; bb = dh_ln_b; w1 = dh_w1; b1 = dh_b1; w2 = dh_w2; w2s = 65; }
    float accb = b1[c];
    for (int k = 0; k < 64; ++k) {
        float wv = w1[k * 64 + c];
        accb += bb[k] * wv;
        unsigned short h, l;
        split_bf(g[k] * wv, h, l);                 // W1'[k][c] stored at [c][k]
        w1hT[i * 4096 + c * 64 + k] = h;
        w1lT[i * 4096 + c * 64 + k] = l;
        split_bf(w2[k * w2s + c], h, l);           // W2[k][c] stored at [c][k]
        w2hT[i * 4096 + c * 64 + k] = h;
        w2lT[i * 4096 + c * 64 + k] = l;
    }
    b1p[i * 64 + c] = accb;
    if (i == 4) w2c[c] = dh_w2[c * 65 + 64];
}

// prep for fused mask: gp[li][c] = ln_pair_g[li][c] * pbs[c],
// cb[li] = sum_c ln_pair_b[li][c]*pbs[c], pbs[c] = sum_h pb_w[li][c][h]. li=0..3.
__global__ void k_maskprep(const float* __restrict__ g, const float* __restrict__ bb,
                           const float* __restrict__ pbw, float* __restrict__ gp,
                           float* __restrict__ cb) {
    int li = blockIdx.x;             // layer 0..3
    int c = threadIdx.x;             // 0..63 (one wave)
    const float* pw = pbw + li * PDIM * NHEAD;
    float pbs = pw[c * 4] + pw[c * 4 + 1] + pw[c * 4 + 2] + pw[c * 4 + 3];
    gp[li * 64 + c] = g[li * 64 + c] * pbs;
    float s = wsum(bb[li * 64 + c] * pbs);
    if (c == 0) cb[li] = s;
}

// prep: split+transpose seq weights to bf16 hi/lo [n][k] via 64x64 LDS tiles.
// src: [K][N] row-major, per-layer stride sstride; dst: [N][K], stride dstride.
__global__ void k_split_T(const float* __restrict__ src, unsigned short* __restrict__ dh,
                          unsigned short* __restrict__ dl, int K, int N,
                          int tiles_k, int tiles_n, size_t sstride, size_t dstride) {
    __shared__ float lds[64][65];
    int bid = blockIdx.x;
    int tpl = tiles_k * tiles_n;
    int layer = bid / tpl;
    int rest = bid % tpl;
    int kt = rest / tiles_n, nt = rest % tiles_n;
    const float* s = src + layer * sstride;
    int t = threadIdx.x, c = t & 63, r0 = t >> 6;
    for (int r = r0; r < 64; r += 4)
        lds[r][c] = s[(size_t)(kt * 64 + r) * N + nt * 64 + c];
    __syncthreads();
    unsigned short* oh = dh + layer * dstride;
    unsigned short* ol = dl + layer * dstride;
    for (int r = r0; r < 64; r += 4) {
        float v = lds[c][r];                       // src[kt*64+c][nt*64+r]
        unsigned short h, l;
        split_bf(v, h, l);
        size_t o = (size_t)(nt * 64 + r) * K + kt * 64 + c;
        oh[o] = h;
        ol[o] = l;
    }
}

// ============ generic MFMA seq GEMM ============
// OUT[m][n] = epi( X[m][:]@W + bias[n] + (R?R[m][n]:0) ), M=768 rows.
// W pre-split bf16 hi/lo transposed [n][k]. ONE 32x32 wave-tile per 64-thread
// block; grid = #tiles (spreads small GEMMs across all CUs).
template<bool GELU>
__global__ void __launch_bounds__(64) k_gemm(
    const float* __restrict__ X, const unsigned short* __restrict__ wTh,
    const unsigned short* __restrict__ wTl, const float* __restrict__ bias,
    const float* __restrict__ R, float* __restrict__ OUT, int K, int N) {
    int idx = blockIdx.x;
    int lane = threadIdx.x & 63;
    int pl = lane & 31, hq = lane >> 5;
    int ntiles = N >> 5;
    int mt = idx / ntiles, nt = idx % ntiles;
    const float* xr = X + (size_t)(mt * 32 + pl) * K + 8 * hq;
    const unsigned short* bh = wTh + (size_t)(nt * 32 + pl) * K + 8 * hq;
    const unsigned short* bl = wTl + (size_t)(nt * 32 + pl) * K + 8 * hq;
    int n = nt * 32 + pl;
    float bv = bias[n];
    f32x16 acc;
#pragma unroll
    for (int r = 0; r < 16; ++r) {
        int mr = mt * 32 + (r & 3) + 8 * (r >> 2) + 4 * hq;
        acc[r] = bv + (R ? R[(size_t)mr * N + n] : 0.0f);
    }
#pragma unroll 4
    for (int s = 0; s < K; s += 16) {
        const f32x4* x4 = (const f32x4*)(xr + s);
        f32x4 xa = x4[0], xb = x4[1];
        float xv[8];
#pragma unroll
        for (int j = 0; j < 4; ++j) { xv[j] = xa[j]; xv[4 + j] = xb[j]; }
        u32x4 ah, al;
        pack8(xv, ah, al);
        bf16x8 bhv = *(const bf16x8*)(bh + s);
        bf16x8 blv = *(const bf16x8*)(bl + s);
        acc = MFMA32(as_bf(ah), bhv, acc);
        acc = MFMA32(as_bf(al), bhv, acc);
        acc = MFMA32(as_bf(ah), blv, acc);
    }
#pragma unroll
    for (int r = 0; r < 16; ++r) {
        int mr = mt * 32 + (r & 3) + 8 * (r >> 2) + 4 * hq;
        float v = acc[r];
        OUT[(size_t)mr * N + n] = GELU ? gelu_fast(v) : v;
    }
}

// seq layernorm: one row per block
__global__ void k_ln_seq(const float* __restrict__ h, const float* __restrict__ g,
                         const float* __restrict__ b, float* __restrict__ out) {
    __shared__ float red[8];
    int row = blockIdx.x;
    int t = threadIdx.x;
    int w = t >> 6, lane = t & 63;
    float v = h[row * HD + t];
    float s = wsum(v);
    if (lane == 0) red[w] = s;
    __syncthreads();
    float mean = (red[0] + red[1] + red[2] + red[3]) * (1.0f / HD);
    float d = v - mean;
    float q = wsum(d * d);
    if (lane == 0) red[4 + w] = q;
    __syncthreads();
    float var = (red[4] + red[5] + red[6] + red[7]) * (1.0f / HD);
    out[row * HD + t] = d * rsqrtf(var + 1e-5f) * g[t] + b[t];
}

// attention for one (b, nh, l) per block
__global__ void k_attn(const float* __restrict__ qkv, const float* __restrict__ mask,
                       float* __restrict__ o) {
    __shared__ __align__(16) float qs[64];
    __shared__ float sc[LSEQ];
    __shared__ float red[8];
    __shared__ float op[4][64];
    int bid = blockIdx.x;
    int l = bid % LSEQ;
    int nh = (bid / LSEQ) & 3;
    int b = bid / (LSEQ * NHEAD);
    int t = threadIdx.x;
    int w = t >> 6, lane = t & 63;
    const float* qbase = qkv + ((size_t)(b * LSEQ + l)) * 768 + nh * 64;
    if (t < 64) qs[t] = qbase[t];
    __syncthreads();
    float lmax = -1e30f;
    float myv[2];
#pragma unroll
    for (int it = 0; it < 2; ++it) {
        int m = t + it * 256;
        if (m < LSEQ) {
            const float* kb = qkv + ((size_t)(b * LSEQ + m)) * 768 + 256 + nh * 64;
            const float4* k4 = (const float4*)kb;
            const float4* q4 = (const float4*)qs;
            float acc = 0.0f;
#pragma unroll
            for (int a = 0; a < 16; ++a) {
                float4 kv = k4[a], qv = q4[a];
                acc += qv.x * kv.x + qv.y * kv.y + qv.z * kv.z + qv.w * kv.w;
            }
            float s = acc * 0.125f + mask[l * LSEQ + m];
            myv[it] = s;
            lmax = fmaxf(lmax, s);
        } else myv[it] = -1e30f;
    }
    float wm = wmax(lmax);
    if (lane == 0) red[w] = wm;
    __syncthreads();
    float gmax = fmaxf(fmaxf(red[0], red[1]), fmaxf(red[2], red[3]));
    float lsum = 0.0f;
#pragma unroll
    for (int it = 0; it < 2; ++it) {
        int m = t + it * 256;
        if (m < LSEQ) {
            float e = expf(myv[it] - gmax);
            sc[m] = e;
            lsum += e;
        }
    }
    float ws = wsum(lsum);
    if (lane == 0) red[4 + w] = ws;
    __syncthreads();
    float inv = 1.0f / (red[4] + red[5] + red[6] + red[7]);
    int d = t & 63, gq = t >> 6;
    float part = 0.0f;
    for (int m = gq * 96; m < (gq + 1) * 96; ++m)
        part += sc[m] * qkv[((size_t)(b * LSEQ + m)) * 768 + 512 + nh * 64 + d];
    op[gq][d] = part;
    __syncthreads();
    if (t < 64) {
        float ov = (op[0][t] + op[1][t] + op[2][t] + op[3][t]) * inv;
        o[((size_t)(b * LSEQ + l)) * HD + nh * 64 + t] = ov;
    }
}

// ============ MFMA pair-update: 2-phase LDS weights ============
// Block = 256 threads = 4 waves, 128 j. MODE 0: layer-0 (residual = pair-init
// computed on the fly) + fused next mask. MODE 1: mid layer (residual read) +
// fused next mask. MODE 2: last layer, fused distogram head.
// Residency theory (R9/R10 evidence): reported 128 VGPR excludes ~64 MFMA
// accumulator regs (unified file) -> ~192 total -> 2 waves/SIMD -> 20% occ.
// Late residual read returns arch-VGPR to ~116 (R4 level); bounds (256,3)
// asks the allocator to trim ~10 more to cross the 3-waves/SIMD step
// (budget 512/3 ~ 170). MODE 2 keeps 2 (heavier DIST tail; avoid spill).
template<int MODE>
__global__ void __launch_bounds__(256, (MODE == 2) ? 2 : 3) k_pair_upd(
    const float* __restrict__ ojc,   // centered oj         (B,L,64)
    const float* __restrict__ oic,   // centered oi+outer_b (B,L,64)
    const unsigned short* __restrict__ w1hT, const unsigned short* __restrict__ w1lT,
    const float* __restrict__ b1p,
    const unsigned short* __restrict__ w2hT, const unsigned short* __restrict__ w2lT,
    const float* __restrict__ b2, float* __restrict__ pair,
    const float* __restrict__ gpb, const float* __restrict__ cbv,
    float* __restrict__ mask_out,
    const float* __restrict__ ipi, const float* __restrict__ ipj,
    const float* __restrict__ rel,
    const unsigned short* __restrict__ dw1h, const unsigned short* __restrict__ dw1l,
    const float* __restrict__ db1p,
    const unsigned short* __restrict__ dw2h, const unsigned short* __restrict__ dw2l,
    const float* __restrict__ w2c, const float* __restrict__ db2,
    float* __restrict__ outg) {
    constexpr bool DIST = (MODE == 2);
    __shared__ __align__(16) char smem[DIST ? 33344 : 17472];
    short (*lw)[64][68] = (short (*)[64][68])smem;   // [2][64][68] hi|lo, padded
    int blk = blockIdx.x;            // row*3 + seg
    int row = blk / 3, seg = blk % 3;
    int b = row / LSEQ;
    int t = threadIdx.x;
    int wave = t >> 6, lane = t & 63;
    int pl = lane & 31, hq = lane >> 5;
    int jj = wave * 32 + pl;         // 0..127 within segment
    int p = seg * 128 + jj;
    const float* ojr = ojc + ((size_t)b * LSEQ + p) * 64;
    const float* oir = oic + (size_t)row * 64;
    float* prp = pair + ((size_t)row * LSEQ + p) * 64;

    // ---- v = oj + oi, vectorized ----
    float v[32];
    {
        const f32x4* a4 = (const f32x4*)ojr;
        const f32x4* c4 = (const f32x4*)oir;
#pragma unroll
        for (int s = 0; s < 4; ++s) {
            f32x4 a = a4[4 * s + 2 * hq], aa = a4[4 * s + 2 * hq + 1];
            f32x4 c = c4[4 * s + 2 * hq], cc = c4[4 * s + 2 * hq + 1];
#pragma unroll
            for (int j = 0; j < 4; ++j) {
                v[8 * s + j] = a[j] + c[j];
                v[8 * s + 4 + j] = aa[j] + cc[j];
            }
        }
    }
    stage_w(lw, t, w1hT, w1lT);

    // LN (mean removed upstream) + bf16 hi/lo pack via cvt_pk
    float ss = 0.0f;
#pragma unroll
    for (int i = 0; i < 32; ++i) ss = fmaf(v[i], v[i], ss);
    ss += __shfl_xor(ss, 32);
    float rs = rsqrtf(ss * (1.0f / PDIM) + 1e-5f);
#pragma unroll
    for (int i = 0; i < 32; ++i) v[i] *= rs;
    u32x4 zh[4], zl[4];
#pragma unroll
    for (int s = 0; s < 4; ++s) pack8(v + 8 * s, zh[s], zl[s]);

    const f32x4* b14 = (const f32x4*)b1p;
    f32x4 bi0[4], bi1[4];
#pragma unroll
    for (int g = 0; g < 4; ++g) { bi0[g] = b14[2 * g + hq]; bi1[g] = b14[8 + 2 * g + hq]; }

    __syncthreads();   // w1 staged

    f32x16 acc0, acc1;
#pragma unroll
    for (int r = 0; r < 16; ++r) {
        acc0[r] = bi0[r >> 2][r & 3];
        acc1[r] = bi1[r >> 2][r & 3];
    }
#pragma unroll
    for (int s = 0; s < 4; ++s) {
        int ko = 16 * s + 8 * hq;
        bf16x8 a0h = ld8(&lw[0][pl][ko]);
        bf16x8 a0l = ld8(&lw[1][pl][ko]);
        bf16x8 a1h = ld8(&lw[0][32 + pl][ko]);
        bf16x8 a1l = ld8(&lw[1][32 + pl][ko]);
        bf16x8 zhs = as_bf(zh[s]), zls = as_bf(zl[s]);
        acc0 = MFMA32(a0h, zhs, acc0);
        acc0 = MFMA32(a0h, zls, acc0);
        acc0 = MFMA32(a0l, zhs, acc0);
        acc1 = MFMA32(a1h, zhs, acc1);
        acc1 = MFMA32(a1h, zls, acc1);
        acc1 = MFMA32(a1l, zhs, acc1);
    }
    __syncthreads();   // all waves done reading w1
    stage_w(lw, t, w2hT, w2lT);  // load latency hides under gelu below

    float u0[16], u1[16];
#pragma unroll
    for (int r = 0; r < 16; ++r) { u0[r] = gelu_erf(acc0[r]); u1[r] = gelu_erf(acc1[r]); }

    // residual + bias2 (loaded LATE — R4 position. Early hoist cost +12 VGPR
    // of live range, blocking the 3-waves/SIMD residency step; latency is
    // covered by the shuffle/pack phase below.)
    f32x4 r0[4], r1[4], q0[4], q1[4];
    {
        const f32x4* b24 = (const f32x4*)b2;
        if constexpr (MODE == 0) {
            int l = row % LSEQ;
            int rr_ = p - l; rr_ = rr_ < -32 ? -32 : (rr_ > 32 ? 32 : rr_); rr_ += 32;
            const f32x4* i4 = (const f32x4*)(ipi + (size_t)row * 64);
            const f32x4* j4 = (const f32x4*)(ipj + ((size_t)b * LSEQ + p) * 64);
            const f32x4* e4 = (const f32x4*)(rel + rr_ * 64);
#pragma unroll
            for (int g = 0; g < 4; ++g) {
                r0[g] = i4[2 * g + hq] + j4[2 * g + hq] + e4[2 * g + hq];
                r1[g] = i4[8 + 2 * g + hq] + j4[8 + 2 * g + hq] + e4[8 + 2 * g + hq];
                q0[g] = b24[2 * g + hq];
                q1[g] = b24[8 + 2 * g + hq];
            }
        } else {
            const f32x4* pr4 = (const f32x4*)prp;
#pragma unroll
            for (int g = 0; g < 4; ++g) {
                r0[g] = pr4[2 * g + hq];
                r1[g] = pr4[8 + 2 * g + hq];
                q0[g] = b24[2 * g + hq];
                q1[g] = b24[8 + 2 * g + hq];
            }
        }
    }

    float rA0[4], rB0[4], rA1[4], rB1[4];
#pragma unroll
    for (int i = 0; i < 4; ++i) {
        rA0[i] = __shfl_xor(hq ? u0[i] : u0[4 + i], 32);
        rB0[i] = __shfl_xor(hq ? u0[8 + i] : u0[12 + i], 32);
        rA1[i] = __shfl_xor(hq ? u1[i] : u1[4 + i], 32);
        rB1[i] = __shfl_xor(hq ? u1[8 + i] : u1[12 + i], 32);
    }
    u32x4 uh[4], ul[4];
#pragma unroll
    for (int s = 0; s < 4; ++s) {
        int tt = s >> 1, q = s & 1;
        float fg[8];
#pragma unroll
        for (int i = 0; i < 4; ++i) {
            float own_f = q ? (tt ? u1[8 + i] : u0[8 + i]) : (tt ? u1[i] : u0[i]);
            float own_s = q ? (tt ? u1[12 + i] : u0[12 + i]) : (tt ? u1[4 + i] : u0[4 + i]);
            float rcv   = q ? (tt ? rB1[i] : rB0[i]) : (tt ? rA1[i] : rA0[i]);
            fg[i]     = hq ? rcv : own_f;
            fg[4 + i] = hq ? own_s : rcv;
        }
        pack8(fg, uh[s], ul[s]);
    }

    __syncthreads();   // w2 staged

    f32x16 c0, c1;
#pragma unroll
    for (int r = 0; r < 16; ++r) {
        int g = r >> 2, i = r & 3;
        c0[r] = q0[g][i] + r0[g][i];
        c1[r] = q1[g][i] + r1[g][i];
    }
#pragma unroll
    for (int s = 0; s < 4; ++s) {
        int ko = 16 * s + 8 * hq;
        bf16x8 a0h = ld8(&lw[0][pl][ko]);
        bf16x8 a0l = ld8(&lw[1][pl][ko]);
        bf16x8 a1h = ld8(&lw[0][32 + pl][ko]);
        bf16x8 a1l = ld8(&lw[1][32 + pl][ko]);
        bf16x8 uhs = as_bf(uh[s]), uls = as_bf(ul[s]);
        c0 = MFMA32(a0h, uhs, c0);
        c0 = MFMA32(a0h, uls, c0);
        c0 = MFMA32(a0l, uhs, c0);
        c1 = MFMA32(a1h, uhs, c1);
        c1 = MFMA32(a1h, uls, c1);
        c1 = MFMA32(a1l, uhs, c1);
    }

    if constexpr (!DIST) {
        // fused mask for next layer: LN(final pair) . pbsum, mean over b via atomics
        const f32x4* gp4 = (const f32x4*)gpb;
        f32x4 gp0[4], gp1[4];
#pragma unroll
        for (int g = 0; g < 4; ++g) { gp0[g] = gp4[2 * g + hq]; gp1[g] = gp4[8 + 2 * g + hq]; }
        float sv = 0.0f;
#pragma unroll
        for (int r = 0; r < 16; ++r) sv += c0[r] + c1[r];
        sv += __shfl_xor(sv, 32);
        float mean = sv * (1.0f / PDIM);
        float sd2 = 0.0f, sdg = 0.0f;
#pragma unroll 4
        for (int r = 0; r < 16; ++r) {
            int g = r >> 2, i = r & 3;
            float d0 = c0[r] - mean, d1 = c1[r] - mean;
            sd2 = fmaf(d0, d0, sd2);
            sd2 = fmaf(d1, d1, sd2);
            sdg = fmaf(d0, gp0[g][i], sdg);
            sdg = fmaf(d1, gp1[g][i], sdg);
        }
        sd2 += __shfl_xor(sd2, 32);
        sdg += __shfl_xor(sdg, 32);
        float rsv = rsqrtf(sd2 * (1.0f / PDIM) + 1e-5f);
        float dot = rsv * sdg + cbv[0];
        if (hq == 0)
            atomicAdd(mask_out + (row % LSEQ) * LSEQ + p, dot * (1.0f / (BATCH * NHEAD)));
        // store updated pair: lane-private float4 x8
        f32x4* pw4 = (f32x4*)prp;
#pragma unroll
        for (int g = 0; g < 4; ++g) {
            f32x4 s0, s1;
#pragma unroll
            for (int i = 0; i < 4; ++i) { s0[i] = c0[4 * g + i]; s1[i] = c1[4 * g + i]; }
            pw4[2 * g + hq] = s0;
            pw4[8 + 2 * g + hq] = s1;
        }
    } else {
        // ---- fused distogram head; fragment->k-order reorder in registers ----
        float ra[4], rb[4], rc[4], rd[4];
#pragma unroll
        for (int i = 0; i < 4; ++i) {
            ra[i] = __shfl_xor(hq ? c0[i] : c0[4 + i], 32);
            rb[i] = __shfl_xor(hq ? c0[8 + i] : c0[12 + i], 32);
            rc[i] = __shfl_xor(hq ? c1[i] : c1[4 + i], 32);
            rd[i] = __shfl_xor(hq ? c1[8 + i] : c1[12 + i], 32);
        }
        float v2[32];
#pragma unroll
        for (int i = 0; i < 4; ++i) {
            v2[i]      = hq ? ra[i] : c0[i];
            v2[4 + i]  = hq ? c0[4 + i] : ra[i];
            v2[8 + i]  = hq ? rb[i] : c0[8 + i];
            v2[12 + i] = hq ? c0[12 + i] : rb[i];
            v2[16 + i] = hq ? rc[i] : c1[i];
            v2[20 + i] = hq ? c1[4 + i] : rc[i];
            v2[24 + i] = hq ? rd[i] : c1[8 + i];
            v2[28 + i] = hq ? c1[12 + i] : rd[i];
        }
        __syncthreads();   // all waves done reading pu w2
        stage_w(lw, t, dw1h, dw1l);

        float sm = 0.0f;
#pragma unroll
        for (int i = 0; i < 32; ++i) sm += v2[i];
        sm += __shfl_xor(sm, 32);
        float mean = sm * (1.0f / PDIM);
        float ss2 = 0.0f;
#pragma unroll
        for (int i = 0; i < 32; ++i) { v2[i] -= mean; ss2 = fmaf(v2[i], v2[i], ss2); }
        ss2 += __shfl_xor(ss2, 32);
        float rs2 = rsqrtf(ss2 * (1.0f / PDIM) + 1e-5f);
#pragma unroll
        for (int i = 0; i < 32; ++i) v2[i] *= rs2;
#pragma unroll
        for (int s = 0; s < 4; ++s) pack8(v2 + 8 * s, zh[s], zl[s]);

        const f32x4* d14 = (const f32x4*)db1p;
        const f32x4* d24 = (const f32x4*)db2;
        const f32x4* wc4 = (const f32x4*)w2c;
        f32x4 di0[4], di1[4], e0[4], e1[4], wc0[4], wc1[4];
#pragma unroll
        for (int g = 0; g < 4; ++g) {
            di0[g] = d14[2 * g + hq]; di1[g] = d14[8 + 2 * g + hq];
            e0[g] = d24[2 * g + hq];  e1[g] = d24[8 + 2 * g + hq];
            wc0[g] = wc4[2 * g + hq]; wc1[g] = wc4[8 + 2 * g + hq];
        }
        __syncthreads();   // dw1 staged

#pragma unroll
        for (int r = 0; r < 16; ++r) {
            acc0[r] = di0[r >> 2][r & 3];
            acc1[r] = di1[r >> 2][r & 3];
        }
#pragma unroll
        for (int s = 0; s < 4; ++s) {
            int ko = 16 * s + 8 * hq;
            bf16x8 a0h = ld8(&lw[0][pl][ko]);
            bf16x8 a0l = ld8(&lw[1][pl][ko]);
            bf16x8 a1h = ld8(&lw[0][32 + pl][ko]);
            bf16x8 a1l = ld8(&lw[1][32 + pl][ko]);
            bf16x8 zhs = as_bf(zh[s]), zls = as_bf(zl[s]);
            acc0 = MFMA32(a0h, zhs, acc0);
            acc0 = MFMA32(a0h, zls, acc0);
            acc0 = MFMA32(a0l, zhs, acc0);
            acc1 = MFMA32(a1h, zhs, acc1);
            acc1 = MFMA32(a1h, zls, acc1);
            acc1 = MFMA32(a1l, zhs, acc1);
        }
        __syncthreads();   // done reading dw1
        stage_w(lw, t, dw2h, dw2l);

        float p64 = 0.0f;
#pragma unroll
        for (int r = 0; r < 16; ++r) {
            int g = r >> 2, i = r & 3;
            u0[r] = gelu_erf(acc0[r]);
            u1[r] = gelu_erf(acc1[r]);
            p64 = fmaf(u0[r], wc0[g][i], p64);
            p64 = fmaf(u1[r], wc1[g][i], p64);
        }
        p64 += __shfl_xor(p64, 32);
#pragma unroll
        for (int i = 0; i < 4; ++i) {
            rA0[i] = __shfl_xor(hq ? u0[i] : u0[4 + i], 32);
            rB0[i] = __shfl_xor(hq ? u0[8 + i] : u0[12 + i], 32);
            rA1[i] = __shfl_xor(hq ? u1[i] : u1[4 + i], 32);
            rB1[i] = __shfl_xor(hq ? u1[8 + i] : u1[12 + i], 32);
        }
#pragma unroll
        for (int s = 0; s < 4; ++s) {
            int tt = s >> 1, q = s & 1;
            float fg[8];
#pragma unroll
            for (int i = 0; i < 4; ++i) {
                float own_f = q ? (tt ? u1[8 + i] : u0[8 + i]) : (tt ? u1[i] : u0[i]);
                float own_s = q ? (tt ? u1[12 + i] : u0[12 + i]) : (tt ? u1[4 + i] : u0[4 + i]);
                float rcv   = q ? (tt ? rB1[i] : rB0[i]) : (tt ? rA1[i] : rA0[i]);
                fg[i]     = hq ? rcv : own_f;
                fg[4 + i] = hq ? own_s : rcv;
            }
            pack8(fg, uh[s], ul[s]);
        }
        __syncthreads();   // dw2 staged

#pragma unroll
        for (int r = 0; r < 16; ++r) {
            c0[r] = e0[r >> 2][r & 3];
            c1[r] = e1[r >> 2][r & 3];
        }
#pragma unroll
        for (int s = 0; s < 4; ++s) {
            int ko = 16 * s + 8 * hq;
            bf16x8 a0h = ld8(&lw[0][pl][ko]);
            bf16x8 a0l = ld8(&lw[1][pl][ko]);
            bf16x8 a1h = ld8(&lw[0][32 + pl][ko]);
            bf16x8 a1l = ld8(&lw[1][32 + pl][ko]);
            bf16x8 uhs = as_bf(uh[s]), uls = as_bf(ul[s]);
            c0 = MFMA32(a0h, uhs, c0);
            c0 = MFMA32(a0h, uls, c0);
            c0 = MFMA32(a0l, uhs, c0);
            c1 = MFMA32(a1h, uhs, c1);
            c1 = MFMA32(a1h, uls, c1);
            c1 = MFMA32(a1l, uhs, c1);
        }
        __syncthreads();   // lw dead everywhere -> reuse smem as output tile
        float (*pt)[65] = (float (*)[65])smem;
#pragma unroll
        for (int r = 0; r < 16; ++r) {
            int rr = (r & 3) + 8 * (r >> 2) + 4 * hq;
            pt[jj][rr] = c0[r];
            pt[jj][32 + rr] = c1[r];
        }
        if (hq == 0) pt[jj][64] = p64 + db2[64];
        __syncthreads();
        float4* dst = (float4*)(outg + ((size_t)row * LSEQ + seg * 128) * NBINS);
        const float4* srcl = (const float4*)&pt[0][0];
        for (int n = t; n < 128 * NBINS / 4; n += 256) dst[n] = srcl[n];
    }
}

// out = (out + out^T(1,2)) / 2, in place.  One 16x16 (l,m) tile pair per block
// (upper triangle incl diagonal); lanes run along the contiguous 65-bin axis.
__global__ void k_sym(float* __restrict__ out) {
    int u = blockIdx.x;
    int b = 0;
    if (u >= NTRI) { b = 1; u -= NTRI; }
    int lt = 0, rem = NTT;
    while (u >= rem) { u -= rem; ++lt; --rem; }
    int mt = lt + u;
    int t = threadIdx.x;
    int g = t >> 6, lane = t & 63;
    float* ob = out + (size_t)b * LSEQ * LSEQ * NBINS;
    for (int e = g; e < 256; e += 4) {
        int i = e >> 4, j = e & 15;
        if (lt == mt && j < i) continue;
        size_t ia = ((size_t)(lt * 16 + i) * LSEQ + (mt * 16 + j)) * NBINS;
        size_t ib = ((size_t)(mt * 16 + j) * LSEQ + (lt * 16 + i)) * NBINS;
        for (int k = lane; k < NBINS; k += 64) {
            float a = ob[ia + k], c = ob[ib + k];
            float vv = 0.5f * (a + c);
            ob[ia + k] = vv;
            if (ia != ib) ob[ib + k] = vv;
        }
    }
}

extern "C" void kernel_launch(void* const* d_in, const int* in_sizes, int n_in,
                              void* d_out, int out_size, void* d_ws, size_t ws_size,
                              hipStream_t stream) {
    const float* x        = (const float*)d_in[0];
    const float* rp_w     = (const float*)d_in[1];
    const float* rp_b     = (const float*)d_in[2];
    const float* pos      = (const float*)d_in[3];
    const float* pii_w    = (const float*)d_in[4];
    const float* pii_b    = (const float*)d_in[5];
    const float* pij_w    = (const float*)d_in[6];
    const float* pij_b    = (const float*)d_in[7];
    const float* rel_emb  = (const float*)d_in[8];
    const float* ln_seq_g = (const float*)d_in[9];
    const float* ln_seq_b = (const float*)d_in[10];
    const float* ln_pair_g= (const float*)d_in[11];
    const float* ln_pair_b= (const float*)d_in[12];
    const float* pb_w     = (const float*)d_in[13];
    const float* in_w     = (const float*)d_in[14];
    const float* in_b     = (const float*)d_in[15];
    const float* out_w    = (const float*)d_in[16];
    const float* out_b    = (const float*)d_in[17];
    const float* ff_ln_g  = (const float*)d_in[18];
    const float* ff_ln_b  = (const float*)d_in[19];
    const float* ff_w1    = (const float*)d_in[20];
    const float* ff_b1    = (const float*)d_in[21];
    const float* ff_w2    = (const float*)d_in[22];
    const float* ff_b2    = (const float*)d_in[23];
    const float* pu_ln_g  = (const float*)d_in[24];
    const float* pu_ln_b  = (const float*)d_in[25];
    const float* pu_w1    = (const float*)d_in[26];
    const float* pu_b1    = (const float*)d_in[27];
    const float* pu_w2    = (const float*)d_in[28];
    const float* pu_b2    = (const float*)d_in[29];
    const float* outer_w  = (const float*)d_in[30];
    const float* outer_b  = (const float*)d_in[31];
    const float* dh_ln_g  = (const float*)d_in[32];
    const float* dh_ln_b  = (const float*)d_in[33];
    const float* dh_w1    = (const float*)d_in[34];
    const float* dh_b1    = (const float*)d_in[35];
    const float* dh_w2    = (const float*)d_in[36];
    const float* dh_b2    = (const float*)d_in[37];
    float* outp = (float*)d_out;

    float* W = (float*)d_ws;
    float* h    = W;  W += BATCH * LSEQ * HD;
    float* sn   = W;  W += BATCH * LSEQ * HD;
    float* qkv  = W;  W += BATCH * LSEQ * 3 * HD;
    float* ob   = W;  W += BATCH * LSEQ * HD;
    float* mid  = W;  W += BATCH * LSEQ * 4 * HD;
    float* maskA= W;  W += LSEQ * LSEQ;
    float* maskB= W;  W += LSEQ * LSEQ;
    float* poi  = W;  W += BATCH * LSEQ * PDIM;
    float* poj  = W;  W += BATCH * LSEQ * PDIM;
    float* poi0 = W;  W += BATCH * LSEQ * PDIM;   // pair-init projections (kept)
    float* poj0 = W;  W += BATCH * LSEQ * PDIM;
    float* b1p  = W;  W += 5 * 64;
    float* w2c  = W;  W += 64;
    float* gpb  = W;  W += 4 * 64;
    float* cbv  = W;  W += 64;
    unsigned short* w1hT = (unsigned short*)W;  W += 5 * 2048;
    unsigned short* w1lT = (unsigned short*)W;  W += 5 * 2048;
    unsigned short* w2hT = (unsigned short*)W;  W += 5 * 2048;
    unsigned short* w2lT = (unsigned short*)W;  W += 5 * 2048;
    // seq-GEMM split/transposed weights (bf16 hi/lo), per-layer strides in elems
    unsigned short* qwT_h = (unsigned short*)W;  W += 4 * 196608 / 2;
    unsigned short* qwT_l = (unsigned short*)W;  W += 4 * 196608 / 2;
    unsigned short* owT_h = (unsigned short*)W;  W += 4 * 65536 / 2;
    unsigned short* owT_l = (unsigned short*)W;  W += 4 * 65536 / 2;
    unsigned short* f1T_h = (unsigned short*)W;  W += 4 * 262144 / 2;
    unsigned short* f1T_l = (unsigned short*)W;  W += 4 * 262144 / 2;
    unsigned short* f2T_h = (unsigned short*)W;  W += 4 * 262144 / 2;
    unsigned short* f2T_l = (unsigned short*)W;  W += 4 * 262144 / 2;
    float* pair = W;  W += (size_t)BATCH * LSEQ * LSEQ * PDIM;

    const int rows = BATCH * LSEQ;   // 768

    k_prep<<<5, 64, 0, stream>>>(pu_ln_g, pu_ln_b, pu_w1, pu_b1, pu_w2,
                                 dh_ln_g, dh_ln_b, dh_w1, dh_b1, dh_w2,
                                 w1hT, w1lT, w2hT, w2lT, b1p, w2c);
    k_maskprep<<<4, 64, 0, stream>>>(ln_pair_g, ln_pair_b, pb_w, gpb, cbv);
    k_split_T<<<4 * 4 * 12, 256, 0, stream>>>(in_w,  qwT_h, qwT_l, 256, 768,  4, 12, 196608, 196608);
    k_split_T<<<4 * 4 * 4,  256, 0, stream>>>(out_w, owT_h, owT_l, 256, 256,  4, 4,  65536,  65536);
    k_split_T<<<4 * 4 * 16, 256, 0, stream>>>(ff_w1, f1T_h, f1T_l, 256, 1024, 4, 16, 262144, 262144);
    k_split_T<<<4 * 16 * 4, 256, 0, stream>>>(ff_w2, f2T_h, f2T_l, 1024, 256, 16, 4, 262144, 262144);
    k_h_init<<<rows, 256, 0, stream>>>(x, rp_w, rp_b, pos, h);
    k_proj2<<<rows, 128, 0, stream>>>(h, pii_w, pij_w, pii_b, pij_b, 0, poi0, poj0);
    hipMemsetAsync(maskA, 0, LSEQ * LSEQ * sizeof(float), stream);
    // layer-0 mask from on-the-fly pair init (pair never written to HBM here)
    k_mask0<<<rows * 12, 64, 0, stream>>>(poi0, poj0, rel_emb, gpb, cbv, maskA);

    float* mcur = maskA;
    float* mnext = maskB;
    for (int i = 0; i < 4; ++i) {
        k_ln_seq<<<rows, 256, 0, stream>>>(h, ln_seq_g + i * HD, ln_seq_b + i * HD, sn);
        // qkv = sn @ in_w + in_b   (24 x 24 tiles, 1-wave blocks)
        k_gemm<false><<<576, 64, 0, stream>>>(sn, qwT_h + i * 196608, qwT_l + i * 196608,
                                              in_b + i * 768, nullptr, qkv, 256, 768);
        k_attn<<<BATCH * NHEAD * LSEQ, 256, 0, stream>>>(qkv, mcur, ob);
        // h += ob @ out_w + out_b  (24 x 8 tiles)
        k_gemm<false><<<192, 64, 0, stream>>>(ob, owT_h + i * 65536, owT_l + i * 65536,
                                              out_b + i * 256, h, h, 256, 256);
        k_ln_seq<<<rows, 256, 0, stream>>>(h, ff_ln_g + i * HD, ff_ln_b + i * HD, sn);
        // mid = gelu(sn @ ff_w1 + b1)  (24 x 32 tiles)
        k_gemm<true><<<768, 64, 0, stream>>>(sn, f1T_h + i * 262144, f1T_l + i * 262144,
                                             ff_b1 + i * 1024, nullptr, mid, 256, 1024);
        // h += mid @ ff_w2 + b2  (24 x 8 tiles)
        k_gemm<false><<<192, 64, 0, stream>>>(mid, f2T_h + i * 262144, f2T_l + i * 262144,
                                              ff_b2 + i * 256, h, h, 1024, 256);
        // centered oi+outer_b (poi) and centered oj (poj)
        k_proj2<<<rows, 128, 0, stream>>>(h, outer_w + i * 2 * HD * PDIM,
                                          outer_w + i * 2 * HD * PDIM + HD * PDIM,
                                          outer_b + i * PDIM, nullptr, 1, poi, poj);
        if (i == 0) {
            hipMemsetAsync(mnext, 0, LSEQ * LSEQ * sizeof(float), stream);
            // layer 0: residual = pair-init computed in-kernel (no pair read)
            k_pair_upd<0><<<rows * 3, 256, 0, stream>>>(
                poj, poi,
                w1hT, w1lT, b1p, w2hT, w2lT, pu_b2, pair,
                gpb + 64, cbv + 1, mnext, poi0, poj0, rel_emb,
                nullptr, nullptr, nullptr, nullptr, nullptr, nullptr, nullptr, nullptr);
            float* tmp = mcur; mcur = mnext; mnext = tmp;
        } else if (i < 3) {
            hipMemsetAsync(mnext, 0, LSEQ * LSEQ * sizeof(float), stream);
            k_pair_upd<1><<<rows * 3, 256, 0, stream>>>(
                poj, poi,
                w1hT + i * 4096, w1lT + i * 4096, b1p + i * 64,
                w2hT + i * 4096, w2lT + i * 4096, pu_b2 + i * PDIM, pair,
                gpb + (i + 1) * 64, cbv + (i + 1), mnext,
                nullptr, nullptr, nullptr,
                nullptr, nullptr, nullptr, nullptr, nullptr, nullptr, nullptr, nullptr);
            float* tmp = mcur; mcur = mnext; mnext = tmp;
        } else {
            // last layer: pair update fused with distogram head; pair never stored
            k_pair_upd<2><<<rows * 3, 256, 0, stream>>>(
                poj, poi,
                w1hT + 3 * 4096, w1lT + 3 * 4096, b1p + 3 * 64,
                w2hT + 3 * 4096, w2lT + 3 * 4096, pu_b2 + 3 * PDIM, pair,
                nullptr, nullptr, nullptr,
                nullptr, nullptr, nullptr,
                w1hT + 4 * 4096, w1lT + 4 * 4096, b1p + 4 * 64,
                w2hT + 4 * 4096, w2lT + 4 * 4096, w2c, dh_b2, outp);
        }
    }

    k_sym<<<2 * NTRI, 256, 0, stream>>>(outp);
}